// Round 6
// baseline (5652.575 us; speedup 1.0000x reference)
//
#include <hip/hip_runtime.h>
#include <hip/hip_bf16.h>

// RepWalk on MI355X (gfx950). Inputs fp32, output fp32 (verified r4).
// Round 6: LSTM recurrence in ONE dispatch per path, 32 blocks, W (Whh AND Wih)
// VGPR-resident, on-the-fly xproj, h exchanged via RELAXED agent-scope atomics
// (no buffer_wbl2/buffer_inv — r5's ACQ_REL barrier cost 14us/step).

typedef unsigned short u16;
typedef __attribute__((ext_vector_type(8))) short short8;
typedef __attribute__((ext_vector_type(4))) float floatx4;

#define NEGV -1e9f
#define MFMA __builtin_amdgcn_mfma_f32_16x16x32_bf16

__device__ __forceinline__ float bf2f(u16 u) {
    union { unsigned int i; float f; } x; x.i = ((unsigned int)u) << 16; return x.f;
}
__device__ __forceinline__ u16 f2bf(float f) {
    unsigned int u = __float_as_uint(f);
    unsigned int r = (u + 0x7fff + ((u >> 16) & 1)) >> 16;
    return (u16)r;
}
__device__ __forceinline__ float sigm(float x) { return 1.f / (1.f + expf(-x)); }
__device__ __forceinline__ float sigmf_(float x) { return 1.f / (1.f + __expf(-x)); }
__device__ __forceinline__ float tanhf_(float x) {
    float e = __expf(2.f * x); return 1.f - 2.f / (e + 1.f);
}
__device__ __forceinline__ float rdf(const void* p, size_t i, int flag) {
    return flag ? ((const float*)p)[i] : bf2f(((const u16*)p)[i]);
}

// block-j partition of 300 h-dims: 12 x 19 + 4 x 18
__device__ __forceinline__ int nd_of(int j) { return (j < 12) ? 19 : 18; }
__device__ __forceinline__ int dbase_of(int j) { return (j < 12) ? j * 19 : 228 + (j - 12) * 18; }

// ---------------- dtype detect ----------------
__global__ void k_detect(const void* __restrict__ emb, int* __restrict__ flag) {
    __shared__ int cnt;
    if (threadIdx.x == 0) cnt = 0;
    __syncthreads();
    u16 x = ((const u16*)emb)[4096 + threadIdx.x];
    int e = (x >> 7) & 0xFF;
    if (e >= 0x8A) atomicAdd(&cnt, 1);
    __syncthreads();
    if (threadIdx.x == 0) *flag = (cnt > 8) ? 1 : 0;
}

// ---------------- small prep ----------------
__global__ void k_prep_small(const int* __restrict__ text, const int* __restrict__ asp,
                             int* __restrict__ lens) {
    int tid = threadIdx.x;
    if (tid < 64) {
        int c = 0;
        for (int s = 0; s < 128; ++s) c += (text[tid * 128 + s] != 0);
        lens[tid] = c;
    } else if (tid < 128) {
        int b = tid - 64; int c = 0;
        for (int a = 0; a < 8; ++a) c += (asp[b * 8 + a] != 0);
        lens[64 + b] = c;
    }
}

// embeddings for positions [0, csteps) of each batch row -> hi/lo bf16, K pad 320
__global__ void k_embed_pos(const void* __restrict__ emb, const int* __restrict__ ids,
                            int csteps, const int* __restrict__ flag,
                            u16* __restrict__ dhi, u16* __restrict__ dlo) {
    int i = blockIdx.x * 256 + threadIdx.x;
    if (i >= 64 * csteps * 320) return;
    int f = *flag;
    int r = i / 320, k = i - r * 320;
    int id = ids[r];
    float val = (k < 300) ? rdf(emb, (size_t)id * 300 + k, f) : 0.f;
    u16 hi = f2bf(val);
    dhi[i] = hi;
    dlo[i] = f2bf(val - bf2f(hi));
}

// Wih [2,1200,300] -> permuted padded [2560,320] hi/lo
__global__ void k_pad_wih_perm(const void* __restrict__ W, const int* __restrict__ flag,
                               u16* __restrict__ dhi, u16* __restrict__ dlo) {
    int i = blockIdx.x * 256 + threadIdx.x;
    if (i >= 2560 * 320) return;
    int f = *flag;
    int R = i / 320, k = i - R * 320;
    int dir = R / 1280, rr = R - dir * 1280;
    int j = rr / 80, c = rr - j * 80;
    int dp = c >> 2, q = c & 3;
    float val = 0.f;
    if (dp < nd_of(j) && k < 300) {
        int gc = q * 300 + dbase_of(j) + dp;
        val = rdf(W, (size_t)dir * 360000 + (size_t)gc * 300 + k, f);
    }
    u16 hi = f2bf(val);
    dhi[i] = hi;
    dlo[i] = f2bf(val - bf2f(hi));
}

// Whh [2,1200,300] -> permuted [2][1280][328] hi/lo
__global__ void k_whh_perm(const void* __restrict__ W, const int* __restrict__ flag,
                           u16* __restrict__ dhi, u16* __restrict__ dlo) {
    int i = blockIdx.x * 256 + threadIdx.x;
    if (i >= 2 * 1280 * 328) return;
    int f = *flag;
    int dir = i / (1280 * 328), r = i - dir * (1280 * 328);
    int col = r / 328, k = r - col * 328;
    int j = col / 80, c = col - j * 80;
    int dp = c >> 2, q = c & 3;
    float val = 0.f;
    if (dp < nd_of(j) && k < 300) {
        int gc = q * 300 + dbase_of(j) + dp;
        val = rdf(W, (size_t)dir * 360000 + (size_t)gc * 300 + k, f);
    }
    u16 hi = f2bf(val);
    dhi[i] = hi;
    dlo[i] = f2bf(val - bf2f(hi));
}

// bih+bhh -> permuted bias [2560]
__global__ void k_bias_perm(const void* bi, const void* bh, const int* __restrict__ flag,
                            float* __restrict__ dst) {
    int i = blockIdx.x * 256 + threadIdx.x;
    if (i >= 2560) return;
    int f = *flag;
    int dir = i / 1280, rr = i - dir * 1280;
    int j = rr / 80, c = rr - j * 80;
    int dp = c >> 2, q = c & 3;
    float val = 0.f;
    if (dp < nd_of(j)) {
        int gc = q * 300 + dbase_of(j) + dp;
        val = rdf(bi, dir * 1200 + gc, f) + rdf(bh, dir * 1200 + gc, f);
    }
    dst[i] = val;
}

// lin1_W [2,600,1200] -> padded [2,640,1216] hi/lo
__global__ void k_pad_lin1(const void* __restrict__ W, const int* __restrict__ flag,
                           u16* __restrict__ dhi, u16* __restrict__ dlo) {
    int i = blockIdx.x * 256 + threadIdx.x;
    if (i >= 2 * 640 * 1216) return;
    int f = *flag;
    int dir = i / (640 * 1216), r = i - dir * (640 * 1216);
    int n = r / 1216, k = r - n * 1216;
    float val = (n < 600 && k < 1200)
        ? rdf(W, (size_t)dir * 720000 + (size_t)n * 1200 + k, f) : 0.f;
    u16 hi = f2bf(val);
    dhi[i] = hi;
    dlo[i] = f2bf(val - bf2f(hi));
}

// smallf = pw(8192)|l2w(1200)|l2b(2)|fcw(1800)|fcb(3); bl[1280]
__global__ void k_small(const void* pw, const void* l2w, const void* l2b,
                        const void* fcw, const void* fcb, const void* lb,
                        const int* __restrict__ flag,
                        float* __restrict__ dst, float* __restrict__ bl) {
    int i = blockIdx.x * 256 + threadIdx.x;
    int f = *flag;
    if (i < 8192)            dst[i] = rdf(pw, i, f);
    else if (i < 9392)       dst[i] = rdf(l2w, i - 8192, f);
    else if (i < 9394)       dst[i] = rdf(l2b, i - 9392, f);
    else if (i < 11194)      dst[i] = rdf(fcw, i - 9394, f);
    else if (i < 11197)      dst[i] = rdf(fcb, i - 11194, f);
    if (i < 1280) {
        int dir = i / 640, c = i - dir * 640;
        bl[i] = (c < 600) ? rdf(lb, dir * 600 + c, f) : 0.f;
    }
}

// ---------------- MFMA GEMM (lin1 path): C = (Ahi+Alo) @ (Bhi+Blo)^T ----------------
__global__ __launch_bounds__(256) void gemm_bt(
    const u16* __restrict__ Ahi, const u16* __restrict__ Alo, int lda,
    const u16* __restrict__ Bhi, const u16* __restrict__ Blo, int ldb,
    const float* __restrict__ bias,
    float* __restrict__ C, int ldc, int nstore, int K, int mode,
    const float* __restrict__ tg, const float* __restrict__ pw, float* __restrict__ vio,
    int mrowoff)
{
    int tid = threadIdx.x;
    int wave = tid >> 6, lane = tid & 63;
    int l15 = lane & 15, quad = lane >> 4;
    int m0 = blockIdx.x * 64 + wave * 16;
    int n0 = blockIdx.y * 64;

    const u16* Ap  = Ahi + (size_t)(m0 + l15) * lda + quad * 8;
    const u16* Ap2 = Alo + (size_t)(m0 + l15) * lda + quad * 8;
    const u16* Bp  = Bhi + (size_t)(n0 + l15) * ldb + quad * 8;
    const u16* Bp2 = Blo + (size_t)(n0 + l15) * ldb + quad * 8;

    floatx4 acc0 = {0.f, 0.f, 0.f, 0.f};
    floatx4 acc1 = acc0, acc2 = acc0, acc3 = acc0;

    int nk = K >> 5;
    for (int kc = 0; kc < nk; ++kc) {
        int ko = kc * 32;
        short8 bh0 = *(const short8*)(Bp + ko);
        short8 bh1 = *(const short8*)(Bp + (size_t)16 * ldb + ko);
        short8 bh2 = *(const short8*)(Bp + (size_t)32 * ldb + ko);
        short8 bh3 = *(const short8*)(Bp + (size_t)48 * ldb + ko);
        short8 bl0 = *(const short8*)(Bp2 + ko);
        short8 bl1 = *(const short8*)(Bp2 + (size_t)16 * ldb + ko);
        short8 bl2 = *(const short8*)(Bp2 + (size_t)32 * ldb + ko);
        short8 bl3 = *(const short8*)(Bp2 + (size_t)48 * ldb + ko);
        short8 a  = *(const short8*)(Ap + ko);
        short8 al = *(const short8*)(Ap2 + ko);
        acc0 = MFMA(a, bh0, acc0, 0, 0, 0);
        acc1 = MFMA(a, bh1, acc1, 0, 0, 0);
        acc2 = MFMA(a, bh2, acc2, 0, 0, 0);
        acc3 = MFMA(a, bh3, acc3, 0, 0, 0);
        acc0 = MFMA(a, bl0, acc0, 0, 0, 0);
        acc1 = MFMA(a, bl1, acc1, 0, 0, 0);
        acc2 = MFMA(a, bl2, acc2, 0, 0, 0);
        acc3 = MFMA(a, bl3, acc3, 0, 0, 0);
        acc0 = MFMA(al, bh0, acc0, 0, 0, 0);
        acc1 = MFMA(al, bh1, acc1, 0, 0, 0);
        acc2 = MFMA(al, bh2, acc2, 0, 0, 0);
        acc3 = MFMA(al, bh3, acc3, 0, 0, 0);
    }

    #pragma unroll
    for (int c = 0; c < 4; ++c) {
        floatx4 acc = (c == 0) ? acc0 : (c == 1) ? acc1 : (c == 2) ? acc2 : acc3;
        int col = n0 + c * 16 + l15;
        if (col >= nstore) continue;
        float bb = bias[col];
        #pragma unroll
        for (int r = 0; r < 4; ++r) {
            int row = m0 + quad * 4 + r;
            float val = acc[r] + bb;
            if (mode == 1) {
                val = val > 0.f ? val : 0.01f * val;
                int rg = row + mrowoff;
                float t = tg[rg];
                size_t vi = (size_t)rg * 600 + col;
                float vv = vio[vi];
                vio[vi] = pw[rg] * ((1.f - t) * val + t * vv);
            } else {
                C[(size_t)row * ldc + col] = val;
            }
        }
    }
}

// ---------------- single-dispatch MFMA LSTM (both dirs), relaxed-atomic exchange ----
// 32 blocks (dir*16 + j), 320 thr = 5 waves. Whh+Wih slices VGPR-resident.
// xh/xl: [64*T][320] bf16 hi/lo. hq: [2 dir][2 parity][64][304] u32 (bf16 in low16).
// ctr: [2*T] ints. vout rows b*T+p, stride 600, offset dir*300.
__global__ __launch_bounds__(320, 1) void k_lstm2(
    const u16* __restrict__ xh, const u16* __restrict__ xl, int T,
    const u16* __restrict__ wih_h, const u16* __restrict__ wih_l,
    const u16* __restrict__ whh_h, const u16* __restrict__ whh_l,
    const float* __restrict__ bperm, const int* __restrict__ lens,
    float* __restrict__ vout, unsigned int* __restrict__ hq, int* __restrict__ ctr)
{
    __shared__ u16 Ah[64 * 328];
    int tid = threadIdx.x;
    int w = tid >> 6, lane = tid & 63;
    int l15 = lane & 15, quad = lane >> 4;
    int dir = blockIdx.x >> 4, j = blockIdx.x & 15;
    int nd = nd_of(j), dbase = dbase_of(j);
    int c = 16 * w + l15;
    int myd = c >> 2, q = c & 3;
    bool owner = (q == 0) && (myd < nd);
    int gdim = dbase + myd;
    int col = dir * 1280 + j * 80 + c;

    // VGPR-resident weight fragments
    short8 whf[10], wlf[10], iwh[10], iwl[10];
    #pragma unroll
    for (int ks = 0; ks < 10; ++ks) {
        size_t hb = (size_t)col * 328 + quad * 8 + ks * 32;
        whf[ks] = *(const short8*)(whh_h + hb);
        wlf[ks] = *(const short8*)(whh_l + hb);
        size_t ib = (size_t)col * 320 + quad * 8 + ks * 32;
        iwh[ks] = *(const short8*)(wih_h + ib);
        iwl[ks] = *(const short8*)(wih_l + ib);
    }
    float breg = bperm[col];
    int lenv[16]; float creg[16];
    #pragma unroll
    for (int m = 0; m < 4; ++m)
        #pragma unroll
        for (int r = 0; r < 4; ++r) {
            int b = 16 * m + quad * 4 + r;
            lenv[m * 4 + r] = lens[b];
            creg[m * 4 + r] = 0.f;
        }
    // zero LDS tail k=304..327 (never rewritten)
    for (int i = tid; i < 768; i += 320) {
        int row = i / 12, cc = 304 + (i - row * 12) * 2;
        *(unsigned int*)&Ah[row * 328 + cc] = 0u;
    }
    unsigned int* hq_d = hq + (size_t)dir * 2 * 64 * 304;

    for (int s = 0; s < T; ++s) {
        int p = dir ? (T - 1 - s) : s;
        const unsigned int* hsrc = hq_d + (size_t)(s & 1) * 64 * 304;
        unsigned int* hdst = hq_d + (size_t)((s & 1) ^ 1) * 64 * 304;

        // x-part (no LDS dependency)
        floatx4 acc[4];
        #pragma unroll
        for (int m = 0; m < 4; ++m) {
            acc[m][0] = breg; acc[m][1] = breg; acc[m][2] = breg; acc[m][3] = breg;
        }
        #pragma unroll
        for (int ks = 0; ks < 10; ++ks) {
            #pragma unroll
            for (int m = 0; m < 4; ++m) {
                int b = 16 * m + l15;
                size_t xo = (size_t)(b * T + p) * 320 + quad * 8 + ks * 32;
                short8 axh = *(const short8*)(xh + xo);
                short8 axl = *(const short8*)(xl + xo);
                acc[m] = MFMA(axh, iwh[ks], acc[m], 0, 0, 0);
                acc[m] = MFMA(axh, iwl[ks], acc[m], 0, 0, 0);
                acc[m] = MFMA(axl, iwh[ks], acc[m], 0, 0, 0);
            }
        }
        // h: coherent load -> LDS
        __syncthreads();
        for (int i = tid; i < 9728; i += 320) {
            int b = i / 152, dd = i - b * 152;
            unsigned long long vv = __hip_atomic_load(
                (const unsigned long long*)(hsrc + b * 304 + dd * 2),
                __ATOMIC_RELAXED, __HIP_MEMORY_SCOPE_AGENT);
            unsigned int packed = (unsigned int)(vv & 0xffffu) |
                                  (((unsigned int)(vv >> 32) & 0xffffu) << 16);
            *(unsigned int*)&Ah[b * 328 + dd * 2] = packed;
        }
        __syncthreads();
        // h-part MFMAs
        #pragma unroll
        for (int ks = 0; ks < 10; ++ks) {
            #pragma unroll
            for (int m = 0; m < 4; ++m) {
                short8 a = *(const short8*)(Ah + (16 * m + l15) * 328 + ks * 32 + quad * 8);
                acc[m] = MFMA(a, whf[ks], acc[m], 0, 0, 0);
                acc[m] = MFMA(a, wlf[ks], acc[m], 0, 0, 0);
            }
        }
        // gates + state + h publish
        #pragma unroll
        for (int m = 0; m < 4; ++m) {
            #pragma unroll
            for (int r = 0; r < 4; ++r) {
                int idx = m * 4 + r;
                float x0 = acc[m][r];
                float act = (q == 2) ? tanhf_(x0) : sigmf_(x0);
                float gi = act;
                float gf = __shfl_xor(act, 1, 64);
                float gg = __shfl_xor(act, 2, 64);
                float go = __shfl_xor(act, 3, 64);
                float cn = gf * creg[idx] + gi * gg;
                float hn = go * tanhf_(cn);
                int b = 16 * m + quad * 4 + r;
                bool valid = owner && (p < lenv[idx]);
                unsigned int hbits;
                if (valid) {
                    creg[idx] = cn;
                    vout[((size_t)b * T + p) * 600 + dir * 300 + gdim] = hn;
                    hbits = f2bf(hn);
                } else {
                    hbits = Ah[b * 328 + gdim];   // hold frozen state
                }
                if (owner)
                    __hip_atomic_store(&hdst[b * 304 + gdim], hbits,
                                       __ATOMIC_RELAXED, __HIP_MEMORY_SCOPE_AGENT);
            }
        }
        // hand-rolled barrier: drain stores, then relaxed flag (no wbl2/inv)
        asm volatile("s_waitcnt vmcnt(0)" ::: "memory");
        __syncthreads();
        if (tid == 0) {
            int* cp = &ctr[dir * T + p];
            __hip_atomic_fetch_add(cp, 1, __ATOMIC_RELAXED, __HIP_MEMORY_SCOPE_AGENT);
            while (__hip_atomic_load(cp, __ATOMIC_RELAXED, __HIP_MEMORY_SCOPE_AGENT) < 16)
                __builtin_amdgcn_s_sleep(1);
        }
        __syncthreads();
    }
}

// ---------------- attention ----------------
__global__ __launch_bounds__(64) void k_scores(
    const float* __restrict__ v, const float* __restrict__ e,
    const int* __restrict__ text, const int* __restrict__ asp,
    const float* __restrict__ l2w, const float* __restrict__ l2b, int iter,
    float* __restrict__ a_sm, float* __restrict__ tg)
{
    int row = blockIdx.x, b = row >> 7, lane = threadIdx.x;
    float acc[9];
    #pragma unroll
    for (int j = 0; j < 9; ++j) acc[j] = 0.f;
    const float* vrow = v + (size_t)row * 600;
    const float* eb = e + (size_t)b * 4800;
    const float* w2 = l2w + iter * 600;
    for (int d = lane; d < 600; d += 64) {
        float vv = vrow[d];
        #pragma unroll
        for (int a = 0; a < 8; ++a) acc[a] += vv * eb[a * 600 + d];
        acc[8] += vv * w2[d];
    }
    #pragma unroll
    for (int off = 32; off >= 1; off >>= 1) {
        #pragma unroll
        for (int j = 0; j < 9; ++j) acc[j] += __shfl_down(acc[j], off, 64);
    }
    if (lane == 0) {
        tg[row] = sigm(acc[8] + l2b[iter]);
        bool sm = (text[row] != 0);
        float sc[8]; float mx = -INFINITY;
        #pragma unroll
        for (int a = 0; a < 8; ++a) {
            sc[a] = (sm && asp[b * 8 + a] != 0) ? acc[a] : NEGV;
            mx = fmaxf(mx, sc[a]);
        }
        float den = 0.f;
        #pragma unroll
        for (int a = 0; a < 8; ++a) { sc[a] = expf(sc[a] - mx); den += sc[a]; }
        float inv = 1.f / den;
        #pragma unroll
        for (int a = 0; a < 8; ++a) a_sm[(size_t)row * 8 + a] = sc[a] * inv;
    }
}

__global__ void k_midcat(const float* __restrict__ a_sm, const float* __restrict__ e,
                         const float* __restrict__ v, int rowoff,
                         u16* __restrict__ cat_hi, u16* __restrict__ cat_lo)
{
    int d = blockIdx.x * 256 + threadIdx.x;
    int rl = blockIdx.y;
    if (d >= 1216) return;
    int row = rowoff + rl;
    int b = row >> 7;
    float val;
    if (d < 600) {
        const float* as = a_sm + (size_t)row * 8;
        const float* eb = e + (size_t)b * 4800 + d;
        float m = 0.f;
        #pragma unroll
        for (int a = 0; a < 8; ++a) m += as[a] * eb[a * 600];
        val = m;
    } else if (d < 1200) {
        val = v[(size_t)row * 600 + (d - 600)];
    } else {
        val = 0.f;
    }
    u16 hi = f2bf(val);
    cat_hi[(size_t)rl * 1216 + d] = hi;
    cat_lo[(size_t)rl * 1216 + d] = f2bf(val - bf2f(hi));
}

// ---------------- final ----------------
__global__ void k_query(const float* __restrict__ e, const int* __restrict__ asp,
                        float* __restrict__ q) {
    int i = blockIdx.x * 256 + threadIdx.x;
    if (i >= 64 * 600) return;
    int b = i / 600, d = i - b * 600;
    float m = NEGV;
    for (int a = 0; a < 8; ++a)
        if (asp[b * 8 + a] != 0) m = fmaxf(m, e[(size_t)b * 4800 + a * 600 + d]);
    q[i] = m;
}

__global__ __launch_bounds__(128) void k_final(
    const float* __restrict__ v, const float* __restrict__ q,
    const int* __restrict__ text, const float* __restrict__ fcW,
    const float* __restrict__ fcb, const int* __restrict__ flag, void* __restrict__ outv)
{
    __shared__ float red[128];
    __shared__ float al[128];
    __shared__ float zz[600];
    int b = blockIdx.x, s = threadIdx.x;
    const float* vrow = v + (size_t)(b * 128 + s) * 600;
    const float* qb = q + (size_t)b * 600;
    float sc = 0.f;
    for (int d = 0; d < 600; ++d) sc += vrow[d] * qb[d];
    if (text[b * 128 + s] == 0) sc = NEGV;
    red[s] = sc; __syncthreads();
    for (int off = 64; off >= 1; off >>= 1) {
        if (s < off) red[s] = fmaxf(red[s], red[s + off]);
        __syncthreads();
    }
    float mx = red[0]; __syncthreads();
    float ex = expf(sc - mx);
    red[s] = ex; __syncthreads();
    for (int off = 64; off >= 1; off >>= 1) {
        if (s < off) red[s] += red[s + off];
        __syncthreads();
    }
    float alpha = ex / red[0];
    al[s] = alpha; __syncthreads();
    for (int d = s; d < 600; d += 128) {
        float z = 0.f;
        for (int s2 = 0; s2 < 128; ++s2) z += al[s2] * v[(size_t)(b * 128 + s2) * 600 + d];
        zz[d] = z;
    }
    __syncthreads();
    if (s < 3) {
        float o = 0.f;
        for (int d = 0; d < 600; ++d) o += zz[d] * fcW[s * 600 + d];
        o += fcb[s];
        if (*flag) ((float*)outv)[b * 3 + s] = o;
        else       ((u16*)outv)[b * 3 + s] = f2bf(o);
    }
}

// ---------------- host launch ----------------
extern "C" void kernel_launch(void* const* d_in, const int* in_sizes, int n_in,
                              void* d_out, int out_size, void* d_ws, size_t ws_size,
                              hipStream_t stream) {
    const int*  text   = (const int*)d_in[0];
    const int*  asp    = (const int*)d_in[1];
    const void* pw     = d_in[2];
    const void* emb    = d_in[3];
    const void* l1_Wih = d_in[4];
    const void* l1_Whh = d_in[5];
    const void* l1_bih = d_in[6];
    const void* l1_bhh = d_in[7];
    const void* l2_Wih = d_in[8];
    const void* l2_Whh = d_in[9];
    const void* l2_bih = d_in[10];
    const void* l2_bhh = d_in[11];
    const void* lin1_W = d_in[12];
    const void* lin1_b = d_in[13];
    const void* lin2_W = d_in[14];
    const void* lin2_b = d_in[15];
    const void* fcW    = d_in[16];
    const void* fcb    = d_in[17];
    (void)ws_size; (void)n_in; (void)in_sizes; (void)out_size;

    char* w = (char*)d_ws;
    size_t off = 0;
    auto alloc = [&](size_t bytes) -> void* {
        void* p = w + off;
        off += (bytes + 255) & ~(size_t)255;
        return p;
    };
    // ---- persistent (~23 MB) ----
    int*   flag     = (int*)  alloc(4);
    int*   lens     = (int*)  alloc(128ull * 4);
    float* bias_l1  = (float*)alloc(1280ull * 4);
    float* smallf   = (float*)alloc(11197ull * 4);
    float* bperm_t  = (float*)alloc(2560ull * 4);
    float* bperm_a  = (float*)alloc(2560ull * 4);
    float* tg       = (float*)alloc(8192ull * 4);
    float* a_sm     = (float*)alloc(8192ull * 8 * 4);
    float* query    = (float*)alloc(64ull * 600 * 4);
    unsigned int* hq_t = (unsigned int*)alloc(2ull * 2 * 64 * 304 * 4);
    unsigned int* hq_a = (unsigned int*)alloc(2ull * 2 * 64 * 304 * 4);
    int*   ctr      = (int*)  alloc(512ull * 4);
    float* e        = (float*)alloc(512ull * 600 * 4);
    float* v        = (float*)alloc(8192ull * 600 * 4);
    float* pw_f     = smallf;
    float* l2w_f    = smallf + 8192;
    float* l2b_f    = smallf + 9392;
    float* fcW_f    = smallf + 9394;
    float* fcb_f    = smallf + 11194;
    // ---- phase region (union ~26 MB) ----
    size_t phase_off = off;
    // phase A (LSTM)
    u16*   ebt_hi   = (u16*)  alloc(8192ull * 320 * 2);
    u16*   ebt_lo   = (u16*)  alloc(8192ull * 320 * 2);
    u16*   eba_hi   = (u16*)  alloc(512ull * 320 * 2);
    u16*   eba_lo   = (u16*)  alloc(512ull * 320 * 2);
    u16*   wipt_hi  = (u16*)  alloc(2560ull * 320 * 2);
    u16*   wipt_lo  = (u16*)  alloc(2560ull * 320 * 2);
    u16*   wipa_hi  = (u16*)  alloc(2560ull * 320 * 2);
    u16*   wipa_lo  = (u16*)  alloc(2560ull * 320 * 2);
    u16*   whpt_hi  = (u16*)  alloc(2ull * 1280 * 328 * 2);
    u16*   whpt_lo  = (u16*)  alloc(2ull * 1280 * 328 * 2);
    u16*   whpa_hi  = (u16*)  alloc(2ull * 1280 * 328 * 2);
    u16*   whpa_lo  = (u16*)  alloc(2ull * 1280 * 328 * 2);
    // phase B (attention) aliases phase A
    off = phase_off;
    u16*   l1w_hi   = (u16*)  alloc(2ull * 640 * 1216 * 2);
    u16*   l1w_lo   = (u16*)  alloc(2ull * 640 * 1216 * 2);
    u16*   cat_hi   = (u16*)  alloc(4096ull * 1216 * 2);
    u16*   cat_lo   = (u16*)  alloc(4096ull * 1216 * 2);

    hipMemsetAsync(v, 0, 8192ull * 600 * 4, stream);
    hipMemsetAsync(e, 0, 512ull * 600 * 4, stream);
    hipMemsetAsync(hq_t, 0, 2ull * 2 * 64 * 304 * 4, stream);
    hipMemsetAsync(hq_a, 0, 2ull * 2 * 64 * 304 * 4, stream);
    hipMemsetAsync(ctr, 0, 512ull * 4, stream);

    // ---- prep ----
    k_detect<<<1, 256, 0, stream>>>(emb, flag);
    k_prep_small<<<1, 128, 0, stream>>>(text, asp, lens);
    k_pad_wih_perm<<<(2560 * 320 + 255) / 256, 256, 0, stream>>>(l1_Wih, flag, wipt_hi, wipt_lo);
    k_pad_wih_perm<<<(2560 * 320 + 255) / 256, 256, 0, stream>>>(l2_Wih, flag, wipa_hi, wipa_lo);
    k_whh_perm<<<(2 * 1280 * 328 + 255) / 256, 256, 0, stream>>>(l1_Whh, flag, whpt_hi, whpt_lo);
    k_whh_perm<<<(2 * 1280 * 328 + 255) / 256, 256, 0, stream>>>(l2_Whh, flag, whpa_hi, whpa_lo);
    k_bias_perm<<<10, 256, 0, stream>>>(l1_bih, l1_bhh, flag, bperm_t);
    k_bias_perm<<<10, 256, 0, stream>>>(l2_bih, l2_bhh, flag, bperm_a);
    k_small<<<49, 256, 0, stream>>>(pw, lin2_W, lin2_b, fcW, fcb, lin1_b, flag,
                                    smallf, bias_l1);

    // ---- embeddings (all positions) ----
    k_embed_pos<<<(512 * 320 + 255) / 256, 256, 0, stream>>>(emb, asp, 8, flag,
                                                             eba_hi, eba_lo);
    k_embed_pos<<<(8192 * 320 + 255) / 256, 256, 0, stream>>>(emb, text, 128, flag,
                                                              ebt_hi, ebt_lo);

    // ---- recurrences (one dispatch each) ----
    k_lstm2<<<32, 320, 0, stream>>>(eba_hi, eba_lo, 8, wipa_hi, wipa_lo,
        whpa_hi, whpa_lo, bperm_a, lens + 64, e, hq_a, ctr + 256);
    k_lstm2<<<32, 320, 0, stream>>>(ebt_hi, ebt_lo, 128, wipt_hi, wipt_lo,
        whpt_hi, whpt_lo, bperm_t, lens, v, hq_t, ctr);

    // ---- phase B prep ----
    k_pad_lin1<<<(2 * 640 * 1216 + 255) / 256, 256, 0, stream>>>(lin1_W, flag,
                                                                 l1w_hi, l1w_lo);

    // ---- two attention iterations (2 chunks of 4096 rows) ----
    for (int iter = 0; iter < 2; ++iter) {
        k_scores<<<8192, 64, 0, stream>>>(v, e, text, asp, l2w_f, l2b_f, iter, a_sm, tg);
        for (int c = 0; c < 2; ++c) {
            int rowoff = c * 4096;
            k_midcat<<<dim3(5, 4096), 256, 0, stream>>>(a_sm, e, v, rowoff, cat_hi, cat_lo);
            gemm_bt<<<dim3(64, 10), 256, 0, stream>>>(cat_hi, cat_lo, 1216,
                l1w_hi + (size_t)iter * 640 * 1216, l1w_lo + (size_t)iter * 640 * 1216,
                1216, bias_l1 + iter * 640,
                nullptr, 0, 600, 1216, 1, tg, pw_f, v, rowoff);
        }
    }

    // ---- final ----
    k_query<<<150, 256, 0, stream>>>(e, asp, query);
    k_final<<<64, 128, 0, stream>>>(v, query, text, fcW_f, fcb_f, flag, d_out);
}

// Round 7
// 2768.173 us; speedup vs baseline: 2.0420x; 2.0420x over previous
//
#include <hip/hip_runtime.h>
#include <hip/hip_bf16.h>

// RepWalk on MI355X (gfx950). Inputs fp32, output fp32 (verified r4).
// Round 7: cross-block h-exchange abandoned (r5 ACQ_REL: 14us/step; r6 relaxed
// atomics: 35us/step, cache-bypass). Back to r4's sync-free per-(b,dir)-chain
// LSTM, now latency-optimized: 960 threads/block (15 waves), K split 3-way
// (100-iter serial loop instead of 300), fp32 weights via coalesced float4,
// unroll 10 for ~10 outstanding loads. Everything else keeps r6's lean
// attention pipeline (2x4096-row lin1 chunks).

typedef unsigned short u16;
typedef __attribute__((ext_vector_type(8))) short short8;
typedef __attribute__((ext_vector_type(4))) float floatx4;

#define NEGV -1e9f
#define MFMA __builtin_amdgcn_mfma_f32_16x16x32_bf16

__device__ __forceinline__ float bf2f(u16 u) {
    union { unsigned int i; float f; } x; x.i = ((unsigned int)u) << 16; return x.f;
}
__device__ __forceinline__ u16 f2bf(float f) {
    unsigned int u = __float_as_uint(f);
    unsigned int r = (u + 0x7fff + ((u >> 16) & 1)) >> 16;
    return (u16)r;
}
__device__ __forceinline__ float sigm(float x) { return 1.f / (1.f + expf(-x)); }
__device__ __forceinline__ float rdf(const void* p, size_t i, int flag) {
    return flag ? ((const float*)p)[i] : bf2f(((const u16*)p)[i]);
}

// ---------------- dtype detect ----------------
__global__ void k_detect(const void* __restrict__ emb, int* __restrict__ flag) {
    __shared__ int cnt;
    if (threadIdx.x == 0) cnt = 0;
    __syncthreads();
    u16 x = ((const u16*)emb)[4096 + threadIdx.x];
    int e = (x >> 7) & 0xFF;
    if (e >= 0x8A) atomicAdd(&cnt, 1);
    __syncthreads();
    if (threadIdx.x == 0) *flag = (cnt > 8) ? 1 : 0;
}

// ---------------- small prep ----------------
__global__ void k_prep_small(const int* __restrict__ text, const int* __restrict__ asp,
                             int* __restrict__ lens) {
    int tid = threadIdx.x;
    if (tid < 64) {
        int c = 0;
        for (int s = 0; s < 128; ++s) c += (text[tid * 128 + s] != 0);
        lens[tid] = c;
    } else if (tid < 128) {
        int b = tid - 64; int c = 0;
        for (int a = 0; a < 8; ++a) c += (asp[b * 8 + a] != 0);
        lens[64 + b] = c;
    }
}

// embeddings for positions [base, base+csteps) -> hi/lo bf16, K pad 320
__global__ void k_embed_pos(const void* __restrict__ emb, const int* __restrict__ ids,
                            int base, int csteps, int stride, const int* __restrict__ flag,
                            u16* __restrict__ dhi, u16* __restrict__ dlo) {
    int i = blockIdx.x * 256 + threadIdx.x;
    if (i >= 64 * csteps * 320) return;
    int f = *flag;
    int r = i / 320, k = i - r * 320;
    int b = r / csteps, j = r - b * csteps;
    int id = ids[b * stride + base + j];
    float val = (k < 300) ? rdf(emb, (size_t)id * 300 + k, f) : 0.f;
    u16 hi = f2bf(val);
    dhi[i] = hi;
    dlo[i] = f2bf(val - bf2f(hi));
}

// Wih [2,1200,300] -> padded [2432,320] hi/lo (standard gate order)
__global__ void k_pad_wih(const void* __restrict__ W, const int* __restrict__ flag,
                          u16* __restrict__ dhi, u16* __restrict__ dlo) {
    int i = blockIdx.x * 256 + threadIdx.x;
    if (i >= 2432 * 320) return;
    int f = *flag;
    int n = i / 320, k = i - n * 320;
    float val = (n < 2400 && k < 300) ? rdf(W, (size_t)n * 300 + k, f) : 0.f;
    u16 hi = f2bf(val);
    dhi[i] = hi;
    dlo[i] = f2bf(val - bf2f(hi));
}

// Whh [2,1200,300] -> WhhT fp32 [2,300,1200]
__global__ void k_whhT(const void* __restrict__ W, const int* __restrict__ flag,
                       float* __restrict__ dst) {
    int i = blockIdx.x * 256 + threadIdx.x;
    if (i >= 720000) return;
    int f = *flag;
    int dir = i / 360000, r = i - dir * 360000;
    int k = r / 1200, g = r - k * 1200;
    dst[i] = rdf(W, (size_t)dir * 360000 + (size_t)g * 300 + k, f);
}

// bias: bt[2400]=l1_bih+l1_bhh ; ba[2400]=l2
__global__ void k_bias(const void* b1i, const void* b1h, const void* b2i, const void* b2h,
                       const int* __restrict__ flag, float* bt, float* ba) {
    int i = blockIdx.x * 256 + threadIdx.x;
    int f = *flag;
    if (i < 2400) {
        bt[i] = rdf(b1i, i, f) + rdf(b1h, i, f);
        ba[i] = rdf(b2i, i, f) + rdf(b2h, i, f);
    }
}

// lin1_W [2,600,1200] -> padded [2,640,1216] hi/lo
__global__ void k_pad_lin1(const void* __restrict__ W, const int* __restrict__ flag,
                           u16* __restrict__ dhi, u16* __restrict__ dlo) {
    int i = blockIdx.x * 256 + threadIdx.x;
    if (i >= 2 * 640 * 1216) return;
    int f = *flag;
    int dir = i / (640 * 1216), r = i - dir * (640 * 1216);
    int n = r / 1216, k = r - n * 1216;
    float val = (n < 600 && k < 1200)
        ? rdf(W, (size_t)dir * 720000 + (size_t)n * 1200 + k, f) : 0.f;
    u16 hi = f2bf(val);
    dhi[i] = hi;
    dlo[i] = f2bf(val - bf2f(hi));
}

// smallf = pw(8192)|l2w(1200)|l2b(2)|fcw(1800)|fcb(3); bl[1280]
__global__ void k_small(const void* pw, const void* l2w, const void* l2b,
                        const void* fcw, const void* fcb, const void* lb,
                        const int* __restrict__ flag,
                        float* __restrict__ dst, float* __restrict__ bl) {
    int i = blockIdx.x * 256 + threadIdx.x;
    int f = *flag;
    if (i < 8192)            dst[i] = rdf(pw, i, f);
    else if (i < 9392)       dst[i] = rdf(l2w, i - 8192, f);
    else if (i < 9394)       dst[i] = rdf(l2b, i - 9392, f);
    else if (i < 11194)      dst[i] = rdf(fcw, i - 9394, f);
    else if (i < 11197)      dst[i] = rdf(fcb, i - 11194, f);
    if (i < 1280) {
        int dir = i / 640, c = i - dir * 640;
        bl[i] = (c < 600) ? rdf(lb, dir * 600 + c, f) : 0.f;
    }
}

// ---------------- MFMA GEMM: C = (Ahi+Alo)[M,K] @ (Bhi+Blo)[N,K]^T ----------------
__global__ __launch_bounds__(256) void gemm_bt(
    const u16* __restrict__ Ahi, const u16* __restrict__ Alo, int lda,
    const u16* __restrict__ Bhi, const u16* __restrict__ Blo, int ldb,
    const float* __restrict__ bias,
    float* __restrict__ C, int ldc, int nstore, int K, int mode,
    const float* __restrict__ tg, const float* __restrict__ pw, float* __restrict__ vio,
    int mrowoff)
{
    int tid = threadIdx.x;
    int wave = tid >> 6, lane = tid & 63;
    int l15 = lane & 15, quad = lane >> 4;
    int m0 = blockIdx.x * 64 + wave * 16;
    int n0 = blockIdx.y * 64;

    const u16* Ap  = Ahi + (size_t)(m0 + l15) * lda + quad * 8;
    const u16* Ap2 = Alo + (size_t)(m0 + l15) * lda + quad * 8;
    const u16* Bp  = Bhi + (size_t)(n0 + l15) * ldb + quad * 8;
    const u16* Bp2 = Blo + (size_t)(n0 + l15) * ldb + quad * 8;

    floatx4 acc0 = {0.f, 0.f, 0.f, 0.f};
    floatx4 acc1 = acc0, acc2 = acc0, acc3 = acc0;

    int nk = K >> 5;
    for (int kc = 0; kc < nk; ++kc) {
        int ko = kc * 32;
        short8 bh0 = *(const short8*)(Bp + ko);
        short8 bh1 = *(const short8*)(Bp + (size_t)16 * ldb + ko);
        short8 bh2 = *(const short8*)(Bp + (size_t)32 * ldb + ko);
        short8 bh3 = *(const short8*)(Bp + (size_t)48 * ldb + ko);
        short8 bl0 = *(const short8*)(Bp2 + ko);
        short8 bl1 = *(const short8*)(Bp2 + (size_t)16 * ldb + ko);
        short8 bl2 = *(const short8*)(Bp2 + (size_t)32 * ldb + ko);
        short8 bl3 = *(const short8*)(Bp2 + (size_t)48 * ldb + ko);
        short8 a  = *(const short8*)(Ap + ko);
        short8 al = *(const short8*)(Ap2 + ko);
        acc0 = MFMA(a, bh0, acc0, 0, 0, 0);
        acc1 = MFMA(a, bh1, acc1, 0, 0, 0);
        acc2 = MFMA(a, bh2, acc2, 0, 0, 0);
        acc3 = MFMA(a, bh3, acc3, 0, 0, 0);
        acc0 = MFMA(a, bl0, acc0, 0, 0, 0);
        acc1 = MFMA(a, bl1, acc1, 0, 0, 0);
        acc2 = MFMA(a, bl2, acc2, 0, 0, 0);
        acc3 = MFMA(a, bl3, acc3, 0, 0, 0);
        acc0 = MFMA(al, bh0, acc0, 0, 0, 0);
        acc1 = MFMA(al, bh1, acc1, 0, 0, 0);
        acc2 = MFMA(al, bh2, acc2, 0, 0, 0);
        acc3 = MFMA(al, bh3, acc3, 0, 0, 0);
    }

    #pragma unroll
    for (int c = 0; c < 4; ++c) {
        floatx4 acc = (c == 0) ? acc0 : (c == 1) ? acc1 : (c == 2) ? acc2 : acc3;
        int col = n0 + c * 16 + l15;
        if (col >= nstore) continue;
        float bb = bias[col];
        #pragma unroll
        for (int r = 0; r < 4; ++r) {
            int row = m0 + quad * 4 + r;
            float val = acc[r] + bb;
            if (mode == 1) {
                val = val > 0.f ? val : 0.01f * val;
                int rg = row + mrowoff;
                float t = tg[rg];
                size_t vi = (size_t)rg * 600 + col;
                float vv = vio[vi];
                vio[vi] = pw[rg] * ((1.f - t) * val + t * vv);
            } else {
                C[(size_t)row * ldc + col] = val;
            }
        }
    }
}

// ---------------- LSTM recurrence: block per (b,dir), K split 3-way ----------------
// 960 threads = 3 k-groups x 320 (300 active). Group g covers k in [100g,100g+100).
// Thread u handles gate-cols 4u..4u+3: partials to LDS, then 300 threads combine
// partials + xproj (bias folded) -> gates -> h,c. No cross-block communication.
// xf/xb rows: b*rpb + (pos-base), ldx cols. State persists in hst/cst.
__global__ __launch_bounds__(960, 1) void k_lstm3(
    const float* __restrict__ xf, const float* __restrict__ xb, int ldx, int rpb,
    int base_f, int base_b, const float* __restrict__ whhT,
    const int* __restrict__ lens, float* __restrict__ out, int T, int init,
    float* __restrict__ hst, float* __restrict__ cst, int nsteps)
{
    __shared__ float h_s[300];
    __shared__ float part[3][1200];
    int tid = threadIdx.x;
    int g3 = tid / 320, u = tid - g3 * 320;
    bool act = (u < 300);
    int blk = blockIdx.x, b = blk >> 1, dir = blk & 1;
    int len = lens[b];
    float c = 0.f;
    if (tid < 300) {
        h_s[tid] = init ? 0.f : hst[(size_t)blk * 300 + tid];
        c = init ? 0.f : cst[(size_t)blk * 300 + tid];
    }
    __syncthreads();
    const float* wbase = whhT + (size_t)dir * 360000 + (size_t)g3 * 100 * 1200 + 4 * u;

    for (int s = 0; s < nsteps; ++s) {
        int pos = dir ? (base_b + nsteps - 1 - s) : (base_f + s);
        if (pos >= len) continue;           // block-uniform skip
        if (act) {
            float a0 = 0.f, a1 = 0.f, a2 = 0.f, a3 = 0.f;
            const float* wp = wbase;
            const float* hs = h_s + g3 * 100;
            #pragma unroll 10
            for (int i = 0; i < 100; ++i) {
                float hk = hs[i];
                float4 w4 = *(const float4*)wp;
                wp += 1200;
                a0 = fmaf(hk, w4.x, a0);
                a1 = fmaf(hk, w4.y, a1);
                a2 = fmaf(hk, w4.z, a2);
                a3 = fmaf(hk, w4.w, a3);
            }
            part[g3][4 * u + 0] = a0;
            part[g3][4 * u + 1] = a1;
            part[g3][4 * u + 2] = a2;
            part[g3][4 * u + 3] = a3;
        }
        __syncthreads();
        if (tid < 300) {
            const float* xr = dir ? (xb + (size_t)(b * rpb + pos - base_b) * ldx)
                                  : (xf + (size_t)(b * rpb + pos - base_f) * ldx);
            float gi = xr[tid]       + part[0][tid]       + part[1][tid]       + part[2][tid];
            float gf = xr[300 + tid] + part[0][300 + tid] + part[1][300 + tid] + part[2][300 + tid];
            float gg = xr[600 + tid] + part[0][600 + tid] + part[1][600 + tid] + part[2][600 + tid];
            float go = xr[900 + tid] + part[0][900 + tid] + part[1][900 + tid] + part[2][900 + tid];
            gi = sigm(gi); gf = sigm(gf); gg = tanhf(gg); go = sigm(go);
            c = gf * c + gi * gg;
            float hn = go * tanhf(c);
            out[((size_t)b * T + pos) * 600 + dir * 300 + tid] = hn;
            h_s[tid] = hn;
        }
        __syncthreads();
    }
    if (tid < 300) {
        hst[(size_t)blk * 300 + tid] = h_s[tid];
        cst[(size_t)blk * 300 + tid] = c;
    }
}

// ---------------- attention ----------------
__global__ __launch_bounds__(64) void k_scores(
    const float* __restrict__ v, const float* __restrict__ e,
    const int* __restrict__ text, const int* __restrict__ asp,
    const float* __restrict__ l2w, const float* __restrict__ l2b, int iter,
    float* __restrict__ a_sm, float* __restrict__ tg)
{
    int row = blockIdx.x, b = row >> 7, lane = threadIdx.x;
    float acc[9];
    #pragma unroll
    for (int j = 0; j < 9; ++j) acc[j] = 0.f;
    const float* vrow = v + (size_t)row * 600;
    const float* eb = e + (size_t)b * 4800;
    const float* w2 = l2w + iter * 600;
    for (int d = lane; d < 600; d += 64) {
        float vv = vrow[d];
        #pragma unroll
        for (int a = 0; a < 8; ++a) acc[a] += vv * eb[a * 600 + d];
        acc[8] += vv * w2[d];
    }
    #pragma unroll
    for (int off = 32; off >= 1; off >>= 1) {
        #pragma unroll
        for (int j = 0; j < 9; ++j) acc[j] += __shfl_down(acc[j], off, 64);
    }
    if (lane == 0) {
        tg[row] = sigm(acc[8] + l2b[iter]);
        bool sm = (text[row] != 0);
        float sc[8]; float mx = -INFINITY;
        #pragma unroll
        for (int a = 0; a < 8; ++a) {
            sc[a] = (sm && asp[b * 8 + a] != 0) ? acc[a] : NEGV;
            mx = fmaxf(mx, sc[a]);
        }
        float den = 0.f;
        #pragma unroll
        for (int a = 0; a < 8; ++a) { sc[a] = expf(sc[a] - mx); den += sc[a]; }
        float inv = 1.f / den;
        #pragma unroll
        for (int a = 0; a < 8; ++a) a_sm[(size_t)row * 8 + a] = sc[a] * inv;
    }
}

__global__ void k_midcat(const float* __restrict__ a_sm, const float* __restrict__ e,
                         const float* __restrict__ v, int rowoff,
                         u16* __restrict__ cat_hi, u16* __restrict__ cat_lo)
{
    int d = blockIdx.x * 256 + threadIdx.x;
    int rl = blockIdx.y;
    if (d >= 1216) return;
    int row = rowoff + rl;
    int b = row >> 7;
    float val;
    if (d < 600) {
        const float* as = a_sm + (size_t)row * 8;
        const float* eb = e + (size_t)b * 4800 + d;
        float m = 0.f;
        #pragma unroll
        for (int a = 0; a < 8; ++a) m += as[a] * eb[a * 600];
        val = m;
    } else if (d < 1200) {
        val = v[(size_t)row * 600 + (d - 600)];
    } else {
        val = 0.f;
    }
    u16 hi = f2bf(val);
    cat_hi[(size_t)rl * 1216 + d] = hi;
    cat_lo[(size_t)rl * 1216 + d] = f2bf(val - bf2f(hi));
}

// ---------------- final ----------------
__global__ void k_query(const float* __restrict__ e, const int* __restrict__ asp,
                        float* __restrict__ q) {
    int i = blockIdx.x * 256 + threadIdx.x;
    if (i >= 64 * 600) return;
    int b = i / 600, d = i - b * 600;
    float m = NEGV;
    for (int a = 0; a < 8; ++a)
        if (asp[b * 8 + a] != 0) m = fmaxf(m, e[(size_t)b * 4800 + a * 600 + d]);
    q[i] = m;
}

__global__ __launch_bounds__(128) void k_final(
    const float* __restrict__ v, const float* __restrict__ q,
    const int* __restrict__ text, const float* __restrict__ fcW,
    const float* __restrict__ fcb, const int* __restrict__ flag, void* __restrict__ outv)
{
    __shared__ float red[128];
    __shared__ float al[128];
    __shared__ float zz[600];
    int b = blockIdx.x, s = threadIdx.x;
    const float* vrow = v + (size_t)(b * 128 + s) * 600;
    const float* qb = q + (size_t)b * 600;
    float sc = 0.f;
    for (int d = 0; d < 600; ++d) sc += vrow[d] * qb[d];
    if (text[b * 128 + s] == 0) sc = NEGV;
    red[s] = sc; __syncthreads();
    for (int off = 64; off >= 1; off >>= 1) {
        if (s < off) red[s] = fmaxf(red[s], red[s + off]);
        __syncthreads();
    }
    float mx = red[0]; __syncthreads();
    float ex = expf(sc - mx);
    red[s] = ex; __syncthreads();
    for (int off = 64; off >= 1; off >>= 1) {
        if (s < off) red[s] += red[s + off];
        __syncthreads();
    }
    float alpha = ex / red[0];
    al[s] = alpha; __syncthreads();
    for (int d = s; d < 600; d += 128) {
        float z = 0.f;
        for (int s2 = 0; s2 < 128; ++s2) z += al[s2] * v[(size_t)(b * 128 + s2) * 600 + d];
        zz[d] = z;
    }
    __syncthreads();
    if (s < 3) {
        float o = 0.f;
        for (int d = 0; d < 600; ++d) o += zz[d] * fcW[s * 600 + d];
        o += fcb[s];
        if (*flag) ((float*)outv)[b * 3 + s] = o;
        else       ((u16*)outv)[b * 3 + s] = f2bf(o);
    }
}

// ---------------- host launch ----------------
extern "C" void kernel_launch(void* const* d_in, const int* in_sizes, int n_in,
                              void* d_out, int out_size, void* d_ws, size_t ws_size,
                              hipStream_t stream) {
    const int*  text   = (const int*)d_in[0];
    const int*  asp    = (const int*)d_in[1];
    const void* pw     = d_in[2];
    const void* emb    = d_in[3];
    const void* l1_Wih = d_in[4];
    const void* l1_Whh = d_in[5];
    const void* l1_bih = d_in[6];
    const void* l1_bhh = d_in[7];
    const void* l2_Wih = d_in[8];
    const void* l2_Whh = d_in[9];
    const void* l2_bih = d_in[10];
    const void* l2_bhh = d_in[11];
    const void* lin1_W = d_in[12];
    const void* lin1_b = d_in[13];
    const void* lin2_W = d_in[14];
    const void* lin2_b = d_in[15];
    const void* fcW    = d_in[16];
    const void* fcb    = d_in[17];
    (void)ws_size; (void)n_in; (void)in_sizes; (void)out_size;

    char* w = (char*)d_ws;
    size_t off = 0;
    auto alloc = [&](size_t bytes) -> void* {
        void* p = w + off;
        off += (bytes + 255) & ~(size_t)255;
        return p;
    };
    // ---- persistent (~23 MB) ----
    int*   flag     = (int*)  alloc(4);
    int*   lens     = (int*)  alloc(128ull * 4);
    float* bias_t   = (float*)alloc(2400ull * 4);
    float* bias_a   = (float*)alloc(2400ull * 4);
    float* bias_l1  = (float*)alloc(1280ull * 4);
    float* smallf   = (float*)alloc(11197ull * 4);
    float* tg       = (float*)alloc(8192ull * 4);
    float* a_sm     = (float*)alloc(8192ull * 8 * 4);
    float* query    = (float*)alloc(64ull * 600 * 4);
    float* hst_t    = (float*)alloc(128ull * 300 * 4);
    float* cst_t    = (float*)alloc(128ull * 300 * 4);
    float* hst_a    = (float*)alloc(128ull * 300 * 4);
    float* cst_a    = (float*)alloc(128ull * 300 * 4);
    float* e        = (float*)alloc(512ull * 600 * 4);
    float* v        = (float*)alloc(8192ull * 600 * 4);
    float* pw_f     = smallf;
    float* l2w_f    = smallf + 8192;
    float* l2b_f    = smallf + 9392;
    float* fcW_f    = smallf + 9394;
    float* fcb_f    = smallf + 11194;
    // ---- phase region (union ~38 MB) ----
    size_t phase_off = off;
    // phase A (LSTM)
    u16*   wfcf_hi  = (u16*)  alloc(2048ull * 320 * 2);
    u16*   wfcf_lo  = (u16*)  alloc(2048ull * 320 * 2);
    u16*   wfcb_hi  = (u16*)  alloc(2048ull * 320 * 2);
    u16*   wfcb_lo  = (u16*)  alloc(2048ull * 320 * 2);
    u16*   af_hi    = (u16*)  alloc(512ull * 320 * 2);
    u16*   af_lo    = (u16*)  alloc(512ull * 320 * 2);
    u16*   wiht_hi  = (u16*)  alloc(2432ull * 320 * 2);
    u16*   wiht_lo  = (u16*)  alloc(2432ull * 320 * 2);
    u16*   wiha_hi  = (u16*)  alloc(2432ull * 320 * 2);
    u16*   wiha_lo  = (u16*)  alloc(2432ull * 320 * 2);
    float* whhT_t   = (float*)alloc(720000ull * 4);
    float* whhT_a   = (float*)alloc(720000ull * 4);
    float* xf       = (float*)alloc(2048ull * 1200 * 4);   // aliases xproj_a [512][2400]
    float* xb       = (float*)alloc(2048ull * 1200 * 4);
    float* xproj_a  = xf;
    // phase B (attention) aliases phase A
    off = phase_off;
    u16*   l1w_hi   = (u16*)  alloc(2ull * 640 * 1216 * 2);
    u16*   l1w_lo   = (u16*)  alloc(2ull * 640 * 1216 * 2);
    u16*   cat_hi   = (u16*)  alloc(4096ull * 1216 * 2);
    u16*   cat_lo   = (u16*)  alloc(4096ull * 1216 * 2);

    hipMemsetAsync(v, 0, 8192ull * 600 * 4, stream);
    hipMemsetAsync(e, 0, 512ull * 600 * 4, stream);

    // ---- prep ----
    k_detect<<<1, 256, 0, stream>>>(emb, flag);
    k_prep_small<<<1, 128, 0, stream>>>(text, asp, lens);
    k_pad_wih<<<(2432 * 320 + 255) / 256, 256, 0, stream>>>(l1_Wih, flag, wiht_hi, wiht_lo);
    k_pad_wih<<<(2432 * 320 + 255) / 256, 256, 0, stream>>>(l2_Wih, flag, wiha_hi, wiha_lo);
    k_whhT<<<(720000 + 255) / 256, 256, 0, stream>>>(l1_Whh, flag, whhT_t);
    k_whhT<<<(720000 + 255) / 256, 256, 0, stream>>>(l2_Whh, flag, whhT_a);
    k_bias<<<10, 256, 0, stream>>>(l1_bih, l1_bhh, l2_bih, l2_bhh, flag, bias_t, bias_a);
    k_small<<<49, 256, 0, stream>>>(pw, lin2_W, lin2_b, fcW, fcb, lin1_b, flag,
                                    smallf, bias_l1);

    // ---- aspect path (xproj_a aliases xf; completes before text chunks) ----
    k_embed_pos<<<(512 * 320 + 255) / 256, 256, 0, stream>>>(emb, asp, 0, 8, 8, flag,
                                                             af_hi, af_lo);
    gemm_bt<<<dim3(8, 38), 256, 0, stream>>>(af_hi, af_lo, 320, wiha_hi, wiha_lo, 320,
        bias_a, xproj_a, 2400, 2400, 320, 0, nullptr, nullptr, nullptr, 0);
    k_lstm3<<<128, 960, 0, stream>>>(xproj_a, xproj_a + 1200, 2400, 8, 0, 0,
        whhT_a, lens + 64, e, 8, 1, hst_a, cst_a, 8);

    // ---- text path: 4 chunks of 32 positions ----
    for (int kk = 0; kk < 4; ++kk) {
        int bf = 32 * kk;          // fwd base
        int bb = 96 - 32 * kk;     // bwd base (descending consumption)
        k_embed_pos<<<(2048 * 320 + 255) / 256, 256, 0, stream>>>(emb, text, bf, 32, 128,
                                                                  flag, wfcf_hi, wfcf_lo);
        k_embed_pos<<<(2048 * 320 + 255) / 256, 256, 0, stream>>>(emb, text, bb, 32, 128,
                                                                  flag, wfcb_hi, wfcb_lo);
        gemm_bt<<<dim3(32, 19), 256, 0, stream>>>(wfcf_hi, wfcf_lo, 320,
            wiht_hi, wiht_lo, 320, bias_t, xf, 1200, 1200, 320, 0,
            nullptr, nullptr, nullptr, 0);
        gemm_bt<<<dim3(32, 19), 256, 0, stream>>>(wfcb_hi, wfcb_lo, 320,
            wiht_hi + 1200ull * 320, wiht_lo + 1200ull * 320, 320, bias_t + 1200,
            xb, 1200, 1200, 320, 0, nullptr, nullptr, nullptr, 0);
        k_lstm3<<<128, 960, 0, stream>>>(xf, xb, 1200, 32, bf, bb,
            whhT_t, lens, v, 128, kk == 0 ? 1 : 0, hst_t, cst_t, 32);
    }

    // ---- phase B prep ----
    k_pad_lin1<<<(2 * 640 * 1216 + 255) / 256, 256, 0, stream>>>(lin1_W, flag,
                                                                 l1w_hi, l1w_lo);

    // ---- two attention iterations (2 chunks of 4096 rows) ----
    for (int iter = 0; iter < 2; ++iter) {
        k_scores<<<8192, 64, 0, stream>>>(v, e, text, asp, l2w_f, l2b_f, iter, a_sm, tg);
        for (int c = 0; c < 2; ++c) {
            int rowoff = c * 4096;
            k_midcat<<<dim3(5, 4096), 256, 0, stream>>>(a_sm, e, v, rowoff, cat_hi, cat_lo);
            gemm_bt<<<dim3(64, 10), 256, 0, stream>>>(cat_hi, cat_lo, 1216,
                l1w_hi + (size_t)iter * 640 * 1216, l1w_lo + (size_t)iter * 640 * 1216,
                1216, bias_l1 + iter * 640,
                nullptr, 0, 600, 1216, 1, tg, pw_f, v, rowoff);
        }
    }

    // ---- final ----
    k_query<<<150, 256, 0, stream>>>(e, asp, query);
    k_final<<<64, 128, 0, stream>>>(v, query, text, fcW_f, fcb_f, flag, d_out);
}

// Round 8
// 2748.165 us; speedup vs baseline: 2.0569x; 1.0073x over previous
//
#include <hip/hip_runtime.h>
#include <hip/hip_bf16.h>
#include <hip/hip_fp16.h>

// RepWalk on MI355X (gfx950). Inputs fp32, output fp32 (verified r4).
// Round 8: r7 showed the chain-LSTM is per-CU L2-streaming-bound (~118 GB/s/CU
// on the 1.44 MB fp32 Whh re-read per step; waves 5->15 gave only 1.17x).
// Single change: Whh stored fp16 (0.72 MB/block/step, ~1.2e-5 abs err/elem).
// Cross-block weight-stationary designs are dead (r5 ACQ_REL 14us/step,
// r6 relaxed atomics 35us/step cache-bypass).

typedef unsigned short u16;
typedef __attribute__((ext_vector_type(8))) short short8;
typedef __attribute__((ext_vector_type(4))) float floatx4;

#define NEGV -1e9f
#define MFMA __builtin_amdgcn_mfma_f32_16x16x32_bf16

__device__ __forceinline__ float bf2f(u16 u) {
    union { unsigned int i; float f; } x; x.i = ((unsigned int)u) << 16; return x.f;
}
__device__ __forceinline__ u16 f2bf(float f) {
    unsigned int u = __float_as_uint(f);
    unsigned int r = (u + 0x7fff + ((u >> 16) & 1)) >> 16;
    return (u16)r;
}
__device__ __forceinline__ float sigm(float x) { return 1.f / (1.f + expf(-x)); }
__device__ __forceinline__ float rdf(const void* p, size_t i, int flag) {
    return flag ? ((const float*)p)[i] : bf2f(((const u16*)p)[i]);
}

// ---------------- dtype detect ----------------
__global__ void k_detect(const void* __restrict__ emb, int* __restrict__ flag) {
    __shared__ int cnt;
    if (threadIdx.x == 0) cnt = 0;
    __syncthreads();
    u16 x = ((const u16*)emb)[4096 + threadIdx.x];
    int e = (x >> 7) & 0xFF;
    if (e >= 0x8A) atomicAdd(&cnt, 1);
    __syncthreads();
    if (threadIdx.x == 0) *flag = (cnt > 8) ? 1 : 0;
}

// ---------------- small prep ----------------
__global__ void k_prep_small(const int* __restrict__ text, const int* __restrict__ asp,
                             int* __restrict__ lens) {
    int tid = threadIdx.x;
    if (tid < 64) {
        int c = 0;
        for (int s = 0; s < 128; ++s) c += (text[tid * 128 + s] != 0);
        lens[tid] = c;
    } else if (tid < 128) {
        int b = tid - 64; int c = 0;
        for (int a = 0; a < 8; ++a) c += (asp[b * 8 + a] != 0);
        lens[64 + b] = c;
    }
}

// embeddings for positions [base, base+csteps) -> hi/lo bf16, K pad 320
__global__ void k_embed_pos(const void* __restrict__ emb, const int* __restrict__ ids,
                            int base, int csteps, int stride, const int* __restrict__ flag,
                            u16* __restrict__ dhi, u16* __restrict__ dlo) {
    int i = blockIdx.x * 256 + threadIdx.x;
    if (i >= 64 * csteps * 320) return;
    int f = *flag;
    int r = i / 320, k = i - r * 320;
    int b = r / csteps, j = r - b * csteps;
    int id = ids[b * stride + base + j];
    float val = (k < 300) ? rdf(emb, (size_t)id * 300 + k, f) : 0.f;
    u16 hi = f2bf(val);
    dhi[i] = hi;
    dlo[i] = f2bf(val - bf2f(hi));
}

// Wih [2,1200,300] -> padded [2432,320] hi/lo (standard gate order)
__global__ void k_pad_wih(const void* __restrict__ W, const int* __restrict__ flag,
                          u16* __restrict__ dhi, u16* __restrict__ dlo) {
    int i = blockIdx.x * 256 + threadIdx.x;
    if (i >= 2432 * 320) return;
    int f = *flag;
    int n = i / 320, k = i - n * 320;
    float val = (n < 2400 && k < 300) ? rdf(W, (size_t)n * 300 + k, f) : 0.f;
    u16 hi = f2bf(val);
    dhi[i] = hi;
    dlo[i] = f2bf(val - bf2f(hi));
}

// Whh [2,1200,300] -> WhhT fp16 [2,300,1200]
__global__ void k_whhT(const void* __restrict__ W, const int* __restrict__ flag,
                       u16* __restrict__ dst) {
    int i = blockIdx.x * 256 + threadIdx.x;
    if (i >= 720000) return;
    int f = *flag;
    int dir = i / 360000, r = i - dir * 360000;
    int k = r / 1200, g = r - k * 1200;
    float val = rdf(W, (size_t)dir * 360000 + (size_t)g * 300 + k, f);
    __half hh = __float2half(val);
    dst[i] = *reinterpret_cast<u16*>(&hh);
}

// bias: bt[2400]=l1_bih+l1_bhh ; ba[2400]=l2
__global__ void k_bias(const void* b1i, const void* b1h, const void* b2i, const void* b2h,
                       const int* __restrict__ flag, float* bt, float* ba) {
    int i = blockIdx.x * 256 + threadIdx.x;
    int f = *flag;
    if (i < 2400) {
        bt[i] = rdf(b1i, i, f) + rdf(b1h, i, f);
        ba[i] = rdf(b2i, i, f) + rdf(b2h, i, f);
    }
}

// lin1_W [2,600,1200] -> padded [2,640,1216] hi/lo
__global__ void k_pad_lin1(const void* __restrict__ W, const int* __restrict__ flag,
                           u16* __restrict__ dhi, u16* __restrict__ dlo) {
    int i = blockIdx.x * 256 + threadIdx.x;
    if (i >= 2 * 640 * 1216) return;
    int f = *flag;
    int dir = i / (640 * 1216), r = i - dir * (640 * 1216);
    int n = r / 1216, k = r - n * 1216;
    float val = (n < 600 && k < 1200)
        ? rdf(W, (size_t)dir * 720000 + (size_t)n * 1200 + k, f) : 0.f;
    u16 hi = f2bf(val);
    dhi[i] = hi;
    dlo[i] = f2bf(val - bf2f(hi));
}

// smallf = pw(8192)|l2w(1200)|l2b(2)|fcw(1800)|fcb(3); bl[1280]
__global__ void k_small(const void* pw, const void* l2w, const void* l2b,
                        const void* fcw, const void* fcb, const void* lb,
                        const int* __restrict__ flag,
                        float* __restrict__ dst, float* __restrict__ bl) {
    int i = blockIdx.x * 256 + threadIdx.x;
    int f = *flag;
    if (i < 8192)            dst[i] = rdf(pw, i, f);
    else if (i < 9392)       dst[i] = rdf(l2w, i - 8192, f);
    else if (i < 9394)       dst[i] = rdf(l2b, i - 9392, f);
    else if (i < 11194)      dst[i] = rdf(fcw, i - 9394, f);
    else if (i < 11197)      dst[i] = rdf(fcb, i - 11194, f);
    if (i < 1280) {
        int dir = i / 640, c = i - dir * 640;
        bl[i] = (c < 600) ? rdf(lb, dir * 600 + c, f) : 0.f;
    }
}

// ---------------- MFMA GEMM: C = (Ahi+Alo)[M,K] @ (Bhi+Blo)[N,K]^T ----------------
__global__ __launch_bounds__(256) void gemm_bt(
    const u16* __restrict__ Ahi, const u16* __restrict__ Alo, int lda,
    const u16* __restrict__ Bhi, const u16* __restrict__ Blo, int ldb,
    const float* __restrict__ bias,
    float* __restrict__ C, int ldc, int nstore, int K, int mode,
    const float* __restrict__ tg, const float* __restrict__ pw, float* __restrict__ vio,
    int mrowoff)
{
    int tid = threadIdx.x;
    int wave = tid >> 6, lane = tid & 63;
    int l15 = lane & 15, quad = lane >> 4;
    int m0 = blockIdx.x * 64 + wave * 16;
    int n0 = blockIdx.y * 64;

    const u16* Ap  = Ahi + (size_t)(m0 + l15) * lda + quad * 8;
    const u16* Ap2 = Alo + (size_t)(m0 + l15) * lda + quad * 8;
    const u16* Bp  = Bhi + (size_t)(n0 + l15) * ldb + quad * 8;
    const u16* Bp2 = Blo + (size_t)(n0 + l15) * ldb + quad * 8;

    floatx4 acc0 = {0.f, 0.f, 0.f, 0.f};
    floatx4 acc1 = acc0, acc2 = acc0, acc3 = acc0;

    int nk = K >> 5;
    for (int kc = 0; kc < nk; ++kc) {
        int ko = kc * 32;
        short8 bh0 = *(const short8*)(Bp + ko);
        short8 bh1 = *(const short8*)(Bp + (size_t)16 * ldb + ko);
        short8 bh2 = *(const short8*)(Bp + (size_t)32 * ldb + ko);
        short8 bh3 = *(const short8*)(Bp + (size_t)48 * ldb + ko);
        short8 bl0 = *(const short8*)(Bp2 + ko);
        short8 bl1 = *(const short8*)(Bp2 + (size_t)16 * ldb + ko);
        short8 bl2 = *(const short8*)(Bp2 + (size_t)32 * ldb + ko);
        short8 bl3 = *(const short8*)(Bp2 + (size_t)48 * ldb + ko);
        short8 a  = *(const short8*)(Ap + ko);
        short8 al = *(const short8*)(Ap2 + ko);
        acc0 = MFMA(a, bh0, acc0, 0, 0, 0);
        acc1 = MFMA(a, bh1, acc1, 0, 0, 0);
        acc2 = MFMA(a, bh2, acc2, 0, 0, 0);
        acc3 = MFMA(a, bh3, acc3, 0, 0, 0);
        acc0 = MFMA(a, bl0, acc0, 0, 0, 0);
        acc1 = MFMA(a, bl1, acc1, 0, 0, 0);
        acc2 = MFMA(a, bl2, acc2, 0, 0, 0);
        acc3 = MFMA(a, bl3, acc3, 0, 0, 0);
        acc0 = MFMA(al, bh0, acc0, 0, 0, 0);
        acc1 = MFMA(al, bh1, acc1, 0, 0, 0);
        acc2 = MFMA(al, bh2, acc2, 0, 0, 0);
        acc3 = MFMA(al, bh3, acc3, 0, 0, 0);
    }

    #pragma unroll
    for (int c = 0; c < 4; ++c) {
        floatx4 acc = (c == 0) ? acc0 : (c == 1) ? acc1 : (c == 2) ? acc2 : acc3;
        int col = n0 + c * 16 + l15;
        if (col >= nstore) continue;
        float bb = bias[col];
        #pragma unroll
        for (int r = 0; r < 4; ++r) {
            int row = m0 + quad * 4 + r;
            float val = acc[r] + bb;
            if (mode == 1) {
                val = val > 0.f ? val : 0.01f * val;
                int rg = row + mrowoff;
                float t = tg[rg];
                size_t vi = (size_t)rg * 600 + col;
                float vv = vio[vi];
                vio[vi] = pw[rg] * ((1.f - t) * val + t * vv);
            } else {
                C[(size_t)row * ldc + col] = val;
            }
        }
    }
}

// ---------------- LSTM recurrence: block per (b,dir), K split 3-way, fp16 W ----------
// 960 threads = 3 k-groups x 320 (300 active). Group g covers k in [100g,100g+100).
// Thread u handles gate-cols 4u..4u+3 (fp16 x4 = 8B load/iter). Partials to LDS,
// 300 threads combine + xproj (bias folded) -> gates -> h,c. No cross-block comm.
__global__ __launch_bounds__(960, 1) void k_lstm3(
    const float* __restrict__ xf, const float* __restrict__ xb, int ldx, int rpb,
    int base_f, int base_b, const u16* __restrict__ whhT,
    const int* __restrict__ lens, float* __restrict__ out, int T, int init,
    float* __restrict__ hst, float* __restrict__ cst, int nsteps)
{
    __shared__ float h_s[300];
    __shared__ float part[3][1200];
    int tid = threadIdx.x;
    int g3 = tid / 320, u = tid - g3 * 320;
    bool act = (u < 300);
    int blk = blockIdx.x, b = blk >> 1, dir = blk & 1;
    int len = lens[b];
    float c = 0.f;
    if (tid < 300) {
        h_s[tid] = init ? 0.f : hst[(size_t)blk * 300 + tid];
        c = init ? 0.f : cst[(size_t)blk * 300 + tid];
    }
    __syncthreads();
    const u16* wbase = whhT + (size_t)dir * 360000 + (size_t)g3 * 100 * 1200 + 4 * u;

    for (int s = 0; s < nsteps; ++s) {
        int pos = dir ? (base_b + nsteps - 1 - s) : (base_f + s);
        if (pos >= len) continue;           // block-uniform skip
        if (act) {
            float a0 = 0.f, a1 = 0.f, a2 = 0.f, a3 = 0.f;
            const u16* wp = wbase;
            const float* hs = h_s + g3 * 100;
            #pragma unroll 10
            for (int i = 0; i < 100; ++i) {
                float hk = hs[i];
                const __half2* w2 = (const __half2*)wp;
                float2 fa = __half22float2(w2[0]);
                float2 fb = __half22float2(w2[1]);
                wp += 1200;
                a0 = fmaf(hk, fa.x, a0);
                a1 = fmaf(hk, fa.y, a1);
                a2 = fmaf(hk, fb.x, a2);
                a3 = fmaf(hk, fb.y, a3);
            }
            part[g3][4 * u + 0] = a0;
            part[g3][4 * u + 1] = a1;
            part[g3][4 * u + 2] = a2;
            part[g3][4 * u + 3] = a3;
        }
        __syncthreads();
        if (tid < 300) {
            const float* xr = dir ? (xb + (size_t)(b * rpb + pos - base_b) * ldx)
                                  : (xf + (size_t)(b * rpb + pos - base_f) * ldx);
            float gi = xr[tid]       + part[0][tid]       + part[1][tid]       + part[2][tid];
            float gf = xr[300 + tid] + part[0][300 + tid] + part[1][300 + tid] + part[2][300 + tid];
            float gg = xr[600 + tid] + part[0][600 + tid] + part[1][600 + tid] + part[2][600 + tid];
            float go = xr[900 + tid] + part[0][900 + tid] + part[1][900 + tid] + part[2][900 + tid];
            gi = sigm(gi); gf = sigm(gf); gg = tanhf(gg); go = sigm(go);
            c = gf * c + gi * gg;
            float hn = go * tanhf(c);
            out[((size_t)b * T + pos) * 600 + dir * 300 + tid] = hn;
            h_s[tid] = hn;
        }
        __syncthreads();
    }
    if (tid < 300) {
        hst[(size_t)blk * 300 + tid] = h_s[tid];
        cst[(size_t)blk * 300 + tid] = c;
    }
}

// ---------------- attention ----------------
__global__ __launch_bounds__(64) void k_scores(
    const float* __restrict__ v, const float* __restrict__ e,
    const int* __restrict__ text, const int* __restrict__ asp,
    const float* __restrict__ l2w, const float* __restrict__ l2b, int iter,
    float* __restrict__ a_sm, float* __restrict__ tg)
{
    int row = blockIdx.x, b = row >> 7, lane = threadIdx.x;
    float acc[9];
    #pragma unroll
    for (int j = 0; j < 9; ++j) acc[j] = 0.f;
    const float* vrow = v + (size_t)row * 600;
    const float* eb = e + (size_t)b * 4800;
    const float* w2 = l2w + iter * 600;
    for (int d = lane; d < 600; d += 64) {
        float vv = vrow[d];
        #pragma unroll
        for (int a = 0; a < 8; ++a) acc[a] += vv * eb[a * 600 + d];
        acc[8] += vv * w2[d];
    }
    #pragma unroll
    for (int off = 32; off >= 1; off >>= 1) {
        #pragma unroll
        for (int j = 0; j < 9; ++j) acc[j] += __shfl_down(acc[j], off, 64);
    }
    if (lane == 0) {
        tg[row] = sigm(acc[8] + l2b[iter]);
        bool sm = (text[row] != 0);
        float sc[8]; float mx = -INFINITY;
        #pragma unroll
        for (int a = 0; a < 8; ++a) {
            sc[a] = (sm && asp[b * 8 + a] != 0) ? acc[a] : NEGV;
            mx = fmaxf(mx, sc[a]);
        }
        float den = 0.f;
        #pragma unroll
        for (int a = 0; a < 8; ++a) { sc[a] = expf(sc[a] - mx); den += sc[a]; }
        float inv = 1.f / den;
        #pragma unroll
        for (int a = 0; a < 8; ++a) a_sm[(size_t)row * 8 + a] = sc[a] * inv;
    }
}

__global__ void k_midcat(const float* __restrict__ a_sm, const float* __restrict__ e,
                         const float* __restrict__ v, int rowoff,
                         u16* __restrict__ cat_hi, u16* __restrict__ cat_lo)
{
    int d = blockIdx.x * 256 + threadIdx.x;
    int rl = blockIdx.y;
    if (d >= 1216) return;
    int row = rowoff + rl;
    int b = row >> 7;
    float val;
    if (d < 600) {
        const float* as = a_sm + (size_t)row * 8;
        const float* eb = e + (size_t)b * 4800 + d;
        float m = 0.f;
        #pragma unroll
        for (int a = 0; a < 8; ++a) m += as[a] * eb[a * 600];
        val = m;
    } else if (d < 1200) {
        val = v[(size_t)row * 600 + (d - 600)];
    } else {
        val = 0.f;
    }
    u16 hi = f2bf(val);
    cat_hi[(size_t)rl * 1216 + d] = hi;
    cat_lo[(size_t)rl * 1216 + d] = f2bf(val - bf2f(hi));
}

// ---------------- final ----------------
__global__ void k_query(const float* __restrict__ e, const int* __restrict__ asp,
                        float* __restrict__ q) {
    int i = blockIdx.x * 256 + threadIdx.x;
    if (i >= 64 * 600) return;
    int b = i / 600, d = i - b * 600;
    float m = NEGV;
    for (int a = 0; a < 8; ++a)
        if (asp[b * 8 + a] != 0) m = fmaxf(m, e[(size_t)b * 4800 + a * 600 + d]);
    q[i] = m;
}

__global__ __launch_bounds__(128) void k_final(
    const float* __restrict__ v, const float* __restrict__ q,
    const int* __restrict__ text, const float* __restrict__ fcW,
    const float* __restrict__ fcb, const int* __restrict__ flag, void* __restrict__ outv)
{
    __shared__ float red[128];
    __shared__ float al[128];
    __shared__ float zz[600];
    int b = blockIdx.x, s = threadIdx.x;
    const float* vrow = v + (size_t)(b * 128 + s) * 600;
    const float* qb = q + (size_t)b * 600;
    float sc = 0.f;
    for (int d = 0; d < 600; ++d) sc += vrow[d] * qb[d];
    if (text[b * 128 + s] == 0) sc = NEGV;
    red[s] = sc; __syncthreads();
    for (int off = 64; off >= 1; off >>= 1) {
        if (s < off) red[s] = fmaxf(red[s], red[s + off]);
        __syncthreads();
    }
    float mx = red[0]; __syncthreads();
    float ex = expf(sc - mx);
    red[s] = ex; __syncthreads();
    for (int off = 64; off >= 1; off >>= 1) {
        if (s < off) red[s] += red[s + off];
        __syncthreads();
    }
    float alpha = ex / red[0];
    al[s] = alpha; __syncthreads();
    for (int d = s; d < 600; d += 128) {
        float z = 0.f;
        for (int s2 = 0; s2 < 128; ++s2) z += al[s2] * v[(size_t)(b * 128 + s2) * 600 + d];
        zz[d] = z;
    }
    __syncthreads();
    if (s < 3) {
        float o = 0.f;
        for (int d = 0; d < 600; ++d) o += zz[d] * fcW[s * 600 + d];
        o += fcb[s];
        if (*flag) ((float*)outv)[b * 3 + s] = o;
        else       ((u16*)outv)[b * 3 + s] = f2bf(o);
    }
}

// ---------------- host launch ----------------
extern "C" void kernel_launch(void* const* d_in, const int* in_sizes, int n_in,
                              void* d_out, int out_size, void* d_ws, size_t ws_size,
                              hipStream_t stream) {
    const int*  text   = (const int*)d_in[0];
    const int*  asp    = (const int*)d_in[1];
    const void* pw     = d_in[2];
    const void* emb    = d_in[3];
    const void* l1_Wih = d_in[4];
    const void* l1_Whh = d_in[5];
    const void* l1_bih = d_in[6];
    const void* l1_bhh = d_in[7];
    const void* l2_Wih = d_in[8];
    const void* l2_Whh = d_in[9];
    const void* l2_bih = d_in[10];
    const void* l2_bhh = d_in[11];
    const void* lin1_W = d_in[12];
    const void* lin1_b = d_in[13];
    const void* lin2_W = d_in[14];
    const void* lin2_b = d_in[15];
    const void* fcW    = d_in[16];
    const void* fcb    = d_in[17];
    (void)ws_size; (void)n_in; (void)in_sizes; (void)out_size;

    char* w = (char*)d_ws;
    size_t off = 0;
    auto alloc = [&](size_t bytes) -> void* {
        void* p = w + off;
        off += (bytes + 255) & ~(size_t)255;
        return p;
    };
    // ---- persistent (~23 MB) ----
    int*   flag     = (int*)  alloc(4);
    int*   lens     = (int*)  alloc(128ull * 4);
    float* bias_t   = (float*)alloc(2400ull * 4);
    float* bias_a   = (float*)alloc(2400ull * 4);
    float* bias_l1  = (float*)alloc(1280ull * 4);
    float* smallf   = (float*)alloc(11197ull * 4);
    float* tg       = (float*)alloc(8192ull * 4);
    float* a_sm     = (float*)alloc(8192ull * 8 * 4);
    float* query    = (float*)alloc(64ull * 600 * 4);
    float* hst_t    = (float*)alloc(128ull * 300 * 4);
    float* cst_t    = (float*)alloc(128ull * 300 * 4);
    float* hst_a    = (float*)alloc(128ull * 300 * 4);
    float* cst_a    = (float*)alloc(128ull * 300 * 4);
    float* e        = (float*)alloc(512ull * 600 * 4);
    float* v        = (float*)alloc(8192ull * 600 * 4);
    float* pw_f     = smallf;
    float* l2w_f    = smallf + 8192;
    float* l2b_f    = smallf + 9392;
    float* fcW_f    = smallf + 9394;
    float* fcb_f    = smallf + 11194;
    // ---- phase region (union ~38 MB) ----
    size_t phase_off = off;
    // phase A (LSTM)
    u16*   wfcf_hi  = (u16*)  alloc(2048ull * 320 * 2);
    u16*   wfcf_lo  = (u16*)  alloc(2048ull * 320 * 2);
    u16*   wfcb_hi  = (u16*)  alloc(2048ull * 320 * 2);
    u16*   wfcb_lo  = (u16*)  alloc(2048ull * 320 * 2);
    u16*   af_hi    = (u16*)  alloc(512ull * 320 * 2);
    u16*   af_lo    = (u16*)  alloc(512ull * 320 * 2);
    u16*   wiht_hi  = (u16*)  alloc(2432ull * 320 * 2);
    u16*   wiht_lo  = (u16*)  alloc(2432ull * 320 * 2);
    u16*   wiha_hi  = (u16*)  alloc(2432ull * 320 * 2);
    u16*   wiha_lo  = (u16*)  alloc(2432ull * 320 * 2);
    u16*   whhT_t   = (u16*)  alloc(720000ull * 2);   // fp16
    u16*   whhT_a   = (u16*)  alloc(720000ull * 2);   // fp16
    float* xf       = (float*)alloc(2048ull * 1200 * 4);   // aliases xproj_a [512][2400]
    float* xb       = (float*)alloc(2048ull * 1200 * 4);
    float* xproj_a  = xf;
    // phase B (attention) aliases phase A
    off = phase_off;
    u16*   l1w_hi   = (u16*)  alloc(2ull * 640 * 1216 * 2);
    u16*   l1w_lo   = (u16*)  alloc(2ull * 640 * 1216 * 2);
    u16*   cat_hi   = (u16*)  alloc(4096ull * 1216 * 2);
    u16*   cat_lo   = (u16*)  alloc(4096ull * 1216 * 2);

    hipMemsetAsync(v, 0, 8192ull * 600 * 4, stream);
    hipMemsetAsync(e, 0, 512ull * 600 * 4, stream);

    // ---- prep ----
    k_detect<<<1, 256, 0, stream>>>(emb, flag);
    k_prep_small<<<1, 128, 0, stream>>>(text, asp, lens);
    k_pad_wih<<<(2432 * 320 + 255) / 256, 256, 0, stream>>>(l1_Wih, flag, wiht_hi, wiht_lo);
    k_pad_wih<<<(2432 * 320 + 255) / 256, 256, 0, stream>>>(l2_Wih, flag, wiha_hi, wiha_lo);
    k_whhT<<<(720000 + 255) / 256, 256, 0, stream>>>(l1_Whh, flag, whhT_t);
    k_whhT<<<(720000 + 255) / 256, 256, 0, stream>>>(l2_Whh, flag, whhT_a);
    k_bias<<<10, 256, 0, stream>>>(l1_bih, l1_bhh, l2_bih, l2_bhh, flag, bias_t, bias_a);
    k_small<<<49, 256, 0, stream>>>(pw, lin2_W, lin2_b, fcW, fcb, lin1_b, flag,
                                    smallf, bias_l1);

    // ---- aspect path (xproj_a aliases xf; completes before text chunks) ----
    k_embed_pos<<<(512 * 320 + 255) / 256, 256, 0, stream>>>(emb, asp, 0, 8, 8, flag,
                                                             af_hi, af_lo);
    gemm_bt<<<dim3(8, 38), 256, 0, stream>>>(af_hi, af_lo, 320, wiha_hi, wiha_lo, 320,
        bias_a, xproj_a, 2400, 2400, 320, 0, nullptr, nullptr, nullptr, 0);
    k_lstm3<<<128, 960, 0, stream>>>(xproj_a, xproj_a + 1200, 2400, 8, 0, 0,
        whhT_a, lens + 64, e, 8, 1, hst_a, cst_a, 8);

    // ---- text path: 4 chunks of 32 positions ----
    for (int kk = 0; kk < 4; ++kk) {
        int bf = 32 * kk;          // fwd base
        int bb = 96 - 32 * kk;     // bwd base (descending consumption)
        k_embed_pos<<<(2048 * 320 + 255) / 256, 256, 0, stream>>>(emb, text, bf, 32, 128,
                                                                  flag, wfcf_hi, wfcf_lo);
        k_embed_pos<<<(2048 * 320 + 255) / 256, 256, 0, stream>>>(emb, text, bb, 32, 128,
                                                                  flag, wfcb_hi, wfcb_lo);
        gemm_bt<<<dim3(32, 19), 256, 0, stream>>>(wfcf_hi, wfcf_lo, 320,
            wiht_hi, wiht_lo, 320, bias_t, xf, 1200, 1200, 320, 0,
            nullptr, nullptr, nullptr, 0);
        gemm_bt<<<dim3(32, 19), 256, 0, stream>>>(wfcb_hi, wfcb_lo, 320,
            wiht_hi + 1200ull * 320, wiht_lo + 1200ull * 320, 320, bias_t + 1200,
            xb, 1200, 1200, 320, 0, nullptr, nullptr, nullptr, 0);
        k_lstm3<<<128, 960, 0, stream>>>(xf, xb, 1200, 32, bf, bb,
            whhT_t, lens, v, 128, kk == 0 ? 1 : 0, hst_t, cst_t, 32);
    }

    // ---- phase B prep ----
    k_pad_lin1<<<(2 * 640 * 1216 + 255) / 256, 256, 0, stream>>>(lin1_W, flag,
                                                                 l1w_hi, l1w_lo);

    // ---- two attention iterations (2 chunks of 4096 rows) ----
    for (int iter = 0; iter < 2; ++iter) {
        k_scores<<<8192, 64, 0, stream>>>(v, e, text, asp, l2w_f, l2b_f, iter, a_sm, tg);
        for (int c = 0; c < 2; ++c) {
            int rowoff = c * 4096;
            k_midcat<<<dim3(5, 4096), 256, 0, stream>>>(a_sm, e, v, rowoff, cat_hi, cat_lo);
            gemm_bt<<<dim3(64, 10), 256, 0, stream>>>(cat_hi, cat_lo, 1216,
                l1w_hi + (size_t)iter * 640 * 1216, l1w_lo + (size_t)iter * 640 * 1216,
                1216, bias_l1 + iter * 640,
                nullptr, 0, 600, 1216, 1, tg, pw_f, v, rowoff);
        }
    }

    // ---- final ----
    k_query<<<150, 256, 0, stream>>>(e, asp, query);
    k_final<<<64, 128, 0, stream>>>(v, query, text, fcW_f, fcb_f, flag, d_out);
}

// Round 9
// 2077.089 us; speedup vs baseline: 2.7214x; 1.3231x over previous
//
#include <hip/hip_runtime.h>
#include <hip/hip_bf16.h>
#include <hip/hip_fp16.h>

// RepWalk on MI355X (gfx950). Inputs fp32, output fp32 (verified r4).
// Round 9: recurrence is per-CU vmem-INSTRUCTION-throughput bound (r7: 3x waves
// -> no change; r8: half bytes, same instr count -> no change). This round
// halves the instruction count: fp16 W loaded as 16B uint4 (8 cols/thread),
// 6 k-groups x 160 thr x 50 iters = 703 wave-loads/step (was 1406).
// Aspect LSTM fused into chunk-0 dispatch (blocks 128..255).

typedef unsigned short u16;
typedef __attribute__((ext_vector_type(8))) short short8;
typedef __attribute__((ext_vector_type(4))) float floatx4;

#define NEGV -1e9f
#define MFMA __builtin_amdgcn_mfma_f32_16x16x32_bf16

__device__ __forceinline__ float bf2f(u16 u) {
    union { unsigned int i; float f; } x; x.i = ((unsigned int)u) << 16; return x.f;
}
__device__ __forceinline__ u16 f2bf(float f) {
    unsigned int u = __float_as_uint(f);
    unsigned int r = (u + 0x7fff + ((u >> 16) & 1)) >> 16;
    return (u16)r;
}
__device__ __forceinline__ float sigm(float x) { return 1.f / (1.f + expf(-x)); }
__device__ __forceinline__ float rdf(const void* p, size_t i, int flag) {
    return flag ? ((const float*)p)[i] : bf2f(((const u16*)p)[i]);
}

// ---------------- dtype detect ----------------
__global__ void k_detect(const void* __restrict__ emb, int* __restrict__ flag) {
    __shared__ int cnt;
    if (threadIdx.x == 0) cnt = 0;
    __syncthreads();
    u16 x = ((const u16*)emb)[4096 + threadIdx.x];
    int e = (x >> 7) & 0xFF;
    if (e >= 0x8A) atomicAdd(&cnt, 1);
    __syncthreads();
    if (threadIdx.x == 0) *flag = (cnt > 8) ? 1 : 0;
}

// ---------------- small prep ----------------
__global__ void k_prep_small(const int* __restrict__ text, const int* __restrict__ asp,
                             int* __restrict__ lens) {
    int tid = threadIdx.x;
    if (tid < 64) {
        int c = 0;
        for (int s = 0; s < 128; ++s) c += (text[tid * 128 + s] != 0);
        lens[tid] = c;
    } else if (tid < 128) {
        int b = tid - 64; int c = 0;
        for (int a = 0; a < 8; ++a) c += (asp[b * 8 + a] != 0);
        lens[64 + b] = c;
    }
}

// embeddings for positions [base, base+csteps) -> hi/lo bf16, K pad 320
__global__ void k_embed_pos(const void* __restrict__ emb, const int* __restrict__ ids,
                            int base, int csteps, int stride, const int* __restrict__ flag,
                            u16* __restrict__ dhi, u16* __restrict__ dlo) {
    int i = blockIdx.x * 256 + threadIdx.x;
    if (i >= 64 * csteps * 320) return;
    int f = *flag;
    int r = i / 320, k = i - r * 320;
    int b = r / csteps, j = r - b * csteps;
    int id = ids[b * stride + base + j];
    float val = (k < 300) ? rdf(emb, (size_t)id * 300 + k, f) : 0.f;
    u16 hi = f2bf(val);
    dhi[i] = hi;
    dlo[i] = f2bf(val - bf2f(hi));
}

// Wih [2,1200,300] -> padded [2432,320] hi/lo (standard gate order)
__global__ void k_pad_wih(const void* __restrict__ W, const int* __restrict__ flag,
                          u16* __restrict__ dhi, u16* __restrict__ dlo) {
    int i = blockIdx.x * 256 + threadIdx.x;
    if (i >= 2432 * 320) return;
    int f = *flag;
    int n = i / 320, k = i - n * 320;
    float val = (n < 2400 && k < 300) ? rdf(W, (size_t)n * 300 + k, f) : 0.f;
    u16 hi = f2bf(val);
    dhi[i] = hi;
    dlo[i] = f2bf(val - bf2f(hi));
}

// Whh [2,1200,300] -> WhhT fp16 [2,300,1200]
__global__ void k_whhT(const void* __restrict__ W, const int* __restrict__ flag,
                       u16* __restrict__ dst) {
    int i = blockIdx.x * 256 + threadIdx.x;
    if (i >= 720000) return;
    int f = *flag;
    int dir = i / 360000, r = i - dir * 360000;
    int k = r / 1200, g = r - k * 1200;
    float val = rdf(W, (size_t)dir * 360000 + (size_t)g * 300 + k, f);
    __half hh = __float2half(val);
    dst[i] = *reinterpret_cast<u16*>(&hh);
}

// bias: bt[2400]=l1_bih+l1_bhh ; ba[2400]=l2
__global__ void k_bias(const void* b1i, const void* b1h, const void* b2i, const void* b2h,
                       const int* __restrict__ flag, float* bt, float* ba) {
    int i = blockIdx.x * 256 + threadIdx.x;
    int f = *flag;
    if (i < 2400) {
        bt[i] = rdf(b1i, i, f) + rdf(b1h, i, f);
        ba[i] = rdf(b2i, i, f) + rdf(b2h, i, f);
    }
}

// lin1_W [2,600,1200] -> padded [2,640,1216] hi/lo
__global__ void k_pad_lin1(const void* __restrict__ W, const int* __restrict__ flag,
                           u16* __restrict__ dhi, u16* __restrict__ dlo) {
    int i = blockIdx.x * 256 + threadIdx.x;
    if (i >= 2 * 640 * 1216) return;
    int f = *flag;
    int dir = i / (640 * 1216), r = i - dir * (640 * 1216);
    int n = r / 1216, k = r - n * 1216;
    float val = (n < 600 && k < 1200)
        ? rdf(W, (size_t)dir * 720000 + (size_t)n * 1200 + k, f) : 0.f;
    u16 hi = f2bf(val);
    dhi[i] = hi;
    dlo[i] = f2bf(val - bf2f(hi));
}

// smallf = pw(8192)|l2w(1200)|l2b(2)|fcw(1800)|fcb(3); bl[1280]
__global__ void k_small(const void* pw, const void* l2w, const void* l2b,
                        const void* fcw, const void* fcb, const void* lb,
                        const int* __restrict__ flag,
                        float* __restrict__ dst, float* __restrict__ bl) {
    int i = blockIdx.x * 256 + threadIdx.x;
    int f = *flag;
    if (i < 8192)            dst[i] = rdf(pw, i, f);
    else if (i < 9392)       dst[i] = rdf(l2w, i - 8192, f);
    else if (i < 9394)       dst[i] = rdf(l2b, i - 9392, f);
    else if (i < 11194)      dst[i] = rdf(fcw, i - 9394, f);
    else if (i < 11197)      dst[i] = rdf(fcb, i - 11194, f);
    if (i < 1280) {
        int dir = i / 640, c = i - dir * 640;
        bl[i] = (c < 600) ? rdf(lb, dir * 600 + c, f) : 0.f;
    }
}

// ---------------- MFMA GEMM: C = (Ahi+Alo)[M,K] @ (Bhi+Blo)[N,K]^T ----------------
__global__ __launch_bounds__(256) void gemm_bt(
    const u16* __restrict__ Ahi, const u16* __restrict__ Alo, int lda,
    const u16* __restrict__ Bhi, const u16* __restrict__ Blo, int ldb,
    const float* __restrict__ bias,
    float* __restrict__ C, int ldc, int nstore, int K, int mode,
    const float* __restrict__ tg, const float* __restrict__ pw, float* __restrict__ vio,
    int mrowoff)
{
    int tid = threadIdx.x;
    int wave = tid >> 6, lane = tid & 63;
    int l15 = lane & 15, quad = lane >> 4;
    int m0 = blockIdx.x * 64 + wave * 16;
    int n0 = blockIdx.y * 64;

    const u16* Ap  = Ahi + (size_t)(m0 + l15) * lda + quad * 8;
    const u16* Ap2 = Alo + (size_t)(m0 + l15) * lda + quad * 8;
    const u16* Bp  = Bhi + (size_t)(n0 + l15) * ldb + quad * 8;
    const u16* Bp2 = Blo + (size_t)(n0 + l15) * ldb + quad * 8;

    floatx4 acc0 = {0.f, 0.f, 0.f, 0.f};
    floatx4 acc1 = acc0, acc2 = acc0, acc3 = acc0;

    int nk = K >> 5;
    for (int kc = 0; kc < nk; ++kc) {
        int ko = kc * 32;
        short8 bh0 = *(const short8*)(Bp + ko);
        short8 bh1 = *(const short8*)(Bp + (size_t)16 * ldb + ko);
        short8 bh2 = *(const short8*)(Bp + (size_t)32 * ldb + ko);
        short8 bh3 = *(const short8*)(Bp + (size_t)48 * ldb + ko);
        short8 bl0 = *(const short8*)(Bp2 + ko);
        short8 bl1 = *(const short8*)(Bp2 + (size_t)16 * ldb + ko);
        short8 bl2 = *(const short8*)(Bp2 + (size_t)32 * ldb + ko);
        short8 bl3 = *(const short8*)(Bp2 + (size_t)48 * ldb + ko);
        short8 a  = *(const short8*)(Ap + ko);
        short8 al = *(const short8*)(Ap2 + ko);
        acc0 = MFMA(a, bh0, acc0, 0, 0, 0);
        acc1 = MFMA(a, bh1, acc1, 0, 0, 0);
        acc2 = MFMA(a, bh2, acc2, 0, 0, 0);
        acc3 = MFMA(a, bh3, acc3, 0, 0, 0);
        acc0 = MFMA(a, bl0, acc0, 0, 0, 0);
        acc1 = MFMA(a, bl1, acc1, 0, 0, 0);
        acc2 = MFMA(a, bl2, acc2, 0, 0, 0);
        acc3 = MFMA(a, bl3, acc3, 0, 0, 0);
        acc0 = MFMA(al, bh0, acc0, 0, 0, 0);
        acc1 = MFMA(al, bh1, acc1, 0, 0, 0);
        acc2 = MFMA(al, bh2, acc2, 0, 0, 0);
        acc3 = MFMA(al, bh3, acc3, 0, 0, 0);
    }

    #pragma unroll
    for (int c = 0; c < 4; ++c) {
        floatx4 acc = (c == 0) ? acc0 : (c == 1) ? acc1 : (c == 2) ? acc2 : acc3;
        int col = n0 + c * 16 + l15;
        if (col >= nstore) continue;
        float bb = bias[col];
        #pragma unroll
        for (int r = 0; r < 4; ++r) {
            int row = m0 + quad * 4 + r;
            float val = acc[r] + bb;
            if (mode == 1) {
                val = val > 0.f ? val : 0.01f * val;
                int rg = row + mrowoff;
                float t = tg[rg];
                size_t vi = (size_t)rg * 600 + col;
                float vv = vio[vi];
                vio[vi] = pw[rg] * ((1.f - t) * val + t * vv);
            } else {
                C[(size_t)row * ldc + col] = val;
            }
        }
    }
}

// ---------------- LSTM recurrence: block per chain, fp16 W, 16B loads ----------------
// 960 threads = 6 k-groups x 160 (150 active). Group g covers k in [50g,50g+50).
// Thread u handles gate-cols 8u..8u+7 (uint4 = 16B fp16 load/iter -> 703
// wave-loads/step vs r8's 1406). Partials to LDS, 300 threads combine + xproj
// (bias folded) -> gates -> h,c. Blocks >= 128 run the aspect path (fused).
__global__ __launch_bounds__(960, 1) void k_lstm4(
    const float* __restrict__ xf, const float* __restrict__ xb, int ldx, int rpb,
    int base_f, int base_b, const u16* __restrict__ whhT,
    const int* __restrict__ lens, float* __restrict__ out, int T, int init,
    float* __restrict__ hst, float* __restrict__ cst, int nsteps,
    const float* __restrict__ xa, const u16* __restrict__ whhA,
    const int* __restrict__ lensA, float* __restrict__ outA,
    float* __restrict__ hstA, float* __restrict__ cstA)
{
    __shared__ float h_s[300];
    __shared__ float part[6][1200];
    int blk = blockIdx.x;
    if (blk >= 128) {                     // fused aspect chain
        blk -= 128;
        xf = xa; xb = xa + 1200; ldx = 2400; rpb = 8;
        base_f = 0; base_b = 0;
        whhT = whhA; lens = lensA; out = outA; T = 8; init = 1;
        hst = hstA; cst = cstA; nsteps = 8;
    }
    int tid = threadIdx.x;
    int g6 = tid / 160, u = tid - g6 * 160;
    bool act = (u < 150);
    int b = blk >> 1, dir = blk & 1;
    int len = lens[b];
    float c = 0.f;
    if (tid < 300) {
        h_s[tid] = init ? 0.f : hst[(size_t)blk * 300 + tid];
        c = init ? 0.f : cst[(size_t)blk * 300 + tid];
    }
    __syncthreads();
    const u16* wbase = whhT + (size_t)dir * 360000 + (size_t)g6 * 50 * 1200 + 8 * u;

    for (int s = 0; s < nsteps; ++s) {
        int pos = dir ? (base_b + nsteps - 1 - s) : (base_f + s);
        if (pos >= len) continue;           // block-uniform skip
        if (act) {
            float a0 = 0.f, a1 = 0.f, a2 = 0.f, a3 = 0.f;
            float a4 = 0.f, a5 = 0.f, a6 = 0.f, a7 = 0.f;
            const u16* wp = wbase;
            const float* hs = h_s + g6 * 50;
            #pragma unroll 10
            for (int i = 0; i < 50; ++i) {
                float hk = hs[i];
                uint4 wv = *(const uint4*)wp;
                wp += 1200;
                float2 f0 = __half22float2(*(__half2*)&wv.x);
                float2 f1 = __half22float2(*(__half2*)&wv.y);
                float2 f2 = __half22float2(*(__half2*)&wv.z);
                float2 f3 = __half22float2(*(__half2*)&wv.w);
                a0 = fmaf(hk, f0.x, a0); a1 = fmaf(hk, f0.y, a1);
                a2 = fmaf(hk, f1.x, a2); a3 = fmaf(hk, f1.y, a3);
                a4 = fmaf(hk, f2.x, a4); a5 = fmaf(hk, f2.y, a5);
                a6 = fmaf(hk, f3.x, a6); a7 = fmaf(hk, f3.y, a7);
            }
            float* pp = &part[g6][8 * u];
            float4 w0 = {a0, a1, a2, a3};
            float4 w1 = {a4, a5, a6, a7};
            *(float4*)pp = w0;
            *(float4*)(pp + 4) = w1;
        }
        __syncthreads();
        if (tid < 300) {
            const float* xr = dir ? (xb + (size_t)(b * rpb + pos - base_b) * ldx)
                                  : (xf + (size_t)(b * rpb + pos - base_f) * ldx);
            float gi = xr[tid], gf = xr[300 + tid], gg = xr[600 + tid], go = xr[900 + tid];
            #pragma unroll
            for (int g = 0; g < 6; ++g) {
                gi += part[g][tid];
                gf += part[g][300 + tid];
                gg += part[g][600 + tid];
                go += part[g][900 + tid];
            }
            gi = sigm(gi); gf = sigm(gf); gg = tanhf(gg); go = sigm(go);
            c = gf * c + gi * gg;
            float hn = go * tanhf(c);
            out[((size_t)b * T + pos) * 600 + dir * 300 + tid] = hn;
            h_s[tid] = hn;
        }
        __syncthreads();
    }
    if (tid < 300) {
        hst[(size_t)blk * 300 + tid] = h_s[tid];
        cst[(size_t)blk * 300 + tid] = c;
    }
}

// ---------------- attention ----------------
__global__ __launch_bounds__(64) void k_scores(
    const float* __restrict__ v, const float* __restrict__ e,
    const int* __restrict__ text, const int* __restrict__ asp,
    const float* __restrict__ l2w, const float* __restrict__ l2b, int iter,
    float* __restrict__ a_sm, float* __restrict__ tg)
{
    int row = blockIdx.x, b = row >> 7, lane = threadIdx.x;
    float acc[9];
    #pragma unroll
    for (int j = 0; j < 9; ++j) acc[j] = 0.f;
    const float* vrow = v + (size_t)row * 600;
    const float* eb = e + (size_t)b * 4800;
    const float* w2 = l2w + iter * 600;
    for (int d = lane; d < 600; d += 64) {
        float vv = vrow[d];
        #pragma unroll
        for (int a = 0; a < 8; ++a) acc[a] += vv * eb[a * 600 + d];
        acc[8] += vv * w2[d];
    }
    #pragma unroll
    for (int off = 32; off >= 1; off >>= 1) {
        #pragma unroll
        for (int j = 0; j < 9; ++j) acc[j] += __shfl_down(acc[j], off, 64);
    }
    if (lane == 0) {
        tg[row] = sigm(acc[8] + l2b[iter]);
        bool sm = (text[row] != 0);
        float sc[8]; float mx = -INFINITY;
        #pragma unroll
        for (int a = 0; a < 8; ++a) {
            sc[a] = (sm && asp[b * 8 + a] != 0) ? acc[a] : NEGV;
            mx = fmaxf(mx, sc[a]);
        }
        float den = 0.f;
        #pragma unroll
        for (int a = 0; a < 8; ++a) { sc[a] = expf(sc[a] - mx); den += sc[a]; }
        float inv = 1.f / den;
        #pragma unroll
        for (int a = 0; a < 8; ++a) a_sm[(size_t)row * 8 + a] = sc[a] * inv;
    }
}

__global__ void k_midcat(const float* __restrict__ a_sm, const float* __restrict__ e,
                         const float* __restrict__ v, int rowoff,
                         u16* __restrict__ cat_hi, u16* __restrict__ cat_lo)
{
    int d = blockIdx.x * 256 + threadIdx.x;
    int rl = blockIdx.y;
    if (d >= 1216) return;
    int row = rowoff + rl;
    int b = row >> 7;
    float val;
    if (d < 600) {
        const float* as = a_sm + (size_t)row * 8;
        const float* eb = e + (size_t)b * 4800 + d;
        float m = 0.f;
        #pragma unroll
        for (int a = 0; a < 8; ++a) m += as[a] * eb[a * 600];
        val = m;
    } else if (d < 1200) {
        val = v[(size_t)row * 600 + (d - 600)];
    } else {
        val = 0.f;
    }
    u16 hi = f2bf(val);
    cat_hi[(size_t)rl * 1216 + d] = hi;
    cat_lo[(size_t)rl * 1216 + d] = f2bf(val - bf2f(hi));
}

// ---------------- final ----------------
__global__ void k_query(const float* __restrict__ e, const int* __restrict__ asp,
                        float* __restrict__ q) {
    int i = blockIdx.x * 256 + threadIdx.x;
    if (i >= 64 * 600) return;
    int b = i / 600, d = i - b * 600;
    float m = NEGV;
    for (int a = 0; a < 8; ++a)
        if (asp[b * 8 + a] != 0) m = fmaxf(m, e[(size_t)b * 4800 + a * 600 + d]);
    q[i] = m;
}

__global__ __launch_bounds__(128) void k_final(
    const float* __restrict__ v, const float* __restrict__ q,
    const int* __restrict__ text, const float* __restrict__ fcW,
    const float* __restrict__ fcb, const int* __restrict__ flag, void* __restrict__ outv)
{
    __shared__ float red[128];
    __shared__ float al[128];
    __shared__ float zz[600];
    int b = blockIdx.x, s = threadIdx.x;
    const float* vrow = v + (size_t)(b * 128 + s) * 600;
    const float* qb = q + (size_t)b * 600;
    float sc = 0.f;
    for (int d = 0; d < 600; ++d) sc += vrow[d] * qb[d];
    if (text[b * 128 + s] == 0) sc = NEGV;
    red[s] = sc; __syncthreads();
    for (int off = 64; off >= 1; off >>= 1) {
        if (s < off) red[s] = fmaxf(red[s], red[s + off]);
        __syncthreads();
    }
    float mx = red[0]; __syncthreads();
    float ex = expf(sc - mx);
    red[s] = ex; __syncthreads();
    for (int off = 64; off >= 1; off >>= 1) {
        if (s < off) red[s] += red[s + off];
        __syncthreads();
    }
    float alpha = ex / red[0];
    al[s] = alpha; __syncthreads();
    for (int d = s; d < 600; d += 128) {
        float z = 0.f;
        for (int s2 = 0; s2 < 128; ++s2) z += al[s2] * v[(size_t)(b * 128 + s2) * 600 + d];
        zz[d] = z;
    }
    __syncthreads();
    if (s < 3) {
        float o = 0.f;
        for (int d = 0; d < 600; ++d) o += zz[d] * fcW[s * 600 + d];
        o += fcb[s];
        if (*flag) ((float*)outv)[b * 3 + s] = o;
        else       ((u16*)outv)[b * 3 + s] = f2bf(o);
    }
}

// ---------------- host launch ----------------
extern "C" void kernel_launch(void* const* d_in, const int* in_sizes, int n_in,
                              void* d_out, int out_size, void* d_ws, size_t ws_size,
                              hipStream_t stream) {
    const int*  text   = (const int*)d_in[0];
    const int*  asp    = (const int*)d_in[1];
    const void* pw     = d_in[2];
    const void* emb    = d_in[3];
    const void* l1_Wih = d_in[4];
    const void* l1_Whh = d_in[5];
    const void* l1_bih = d_in[6];
    const void* l1_bhh = d_in[7];
    const void* l2_Wih = d_in[8];
    const void* l2_Whh = d_in[9];
    const void* l2_bih = d_in[10];
    const void* l2_bhh = d_in[11];
    const void* lin1_W = d_in[12];
    const void* lin1_b = d_in[13];
    const void* lin2_W = d_in[14];
    const void* lin2_b = d_in[15];
    const void* fcW    = d_in[16];
    const void* fcb    = d_in[17];
    (void)ws_size; (void)n_in; (void)in_sizes; (void)out_size;

    char* w = (char*)d_ws;
    size_t off = 0;
    auto alloc = [&](size_t bytes) -> void* {
        void* p = w + off;
        off += (bytes + 255) & ~(size_t)255;
        return p;
    };
    // ---- persistent (~23 MB) ----
    int*   flag     = (int*)  alloc(4);
    int*   lens     = (int*)  alloc(128ull * 4);
    float* bias_t   = (float*)alloc(2400ull * 4);
    float* bias_a   = (float*)alloc(2400ull * 4);
    float* bias_l1  = (float*)alloc(1280ull * 4);
    float* smallf   = (float*)alloc(11197ull * 4);
    float* tg       = (float*)alloc(8192ull * 4);
    float* a_sm     = (float*)alloc(8192ull * 8 * 4);
    float* query    = (float*)alloc(64ull * 600 * 4);
    float* hst_t    = (float*)alloc(128ull * 300 * 4);
    float* cst_t    = (float*)alloc(128ull * 300 * 4);
    float* hst_a    = (float*)alloc(128ull * 300 * 4);
    float* cst_a    = (float*)alloc(128ull * 300 * 4);
    float* e        = (float*)alloc(512ull * 600 * 4);
    float* v        = (float*)alloc(8192ull * 600 * 4);
    float* pw_f     = smallf;
    float* l2w_f    = smallf + 8192;
    float* l2b_f    = smallf + 9392;
    float* fcW_f    = smallf + 9394;
    float* fcb_f    = smallf + 11194;
    // ---- phase region (union ~38 MB) ----
    size_t phase_off = off;
    // phase A (LSTM)
    u16*   wfcf_hi  = (u16*)  alloc(2048ull * 320 * 2);
    u16*   wfcf_lo  = (u16*)  alloc(2048ull * 320 * 2);
    u16*   wfcb_hi  = (u16*)  alloc(2048ull * 320 * 2);
    u16*   wfcb_lo  = (u16*)  alloc(2048ull * 320 * 2);
    u16*   af_hi    = (u16*)  alloc(512ull * 320 * 2);
    u16*   af_lo    = (u16*)  alloc(512ull * 320 * 2);
    u16*   wiht_hi  = (u16*)  alloc(2432ull * 320 * 2);
    u16*   wiht_lo  = (u16*)  alloc(2432ull * 320 * 2);
    u16*   wiha_hi  = (u16*)  alloc(2432ull * 320 * 2);
    u16*   wiha_lo  = (u16*)  alloc(2432ull * 320 * 2);
    u16*   whhT_t   = (u16*)  alloc(720000ull * 2);   // fp16
    u16*   whhT_a   = (u16*)  alloc(720000ull * 2);   // fp16
    float* xf       = (float*)alloc(2048ull * 1200 * 4);
    float* xb       = (float*)alloc(2048ull * 1200 * 4);
    float* xproj_a  = (float*)alloc(512ull * 2400 * 4);   // separate: alive during chunk 0
    // phase B (attention) aliases phase A
    off = phase_off;
    u16*   l1w_hi   = (u16*)  alloc(2ull * 640 * 1216 * 2);
    u16*   l1w_lo   = (u16*)  alloc(2ull * 640 * 1216 * 2);
    u16*   cat_hi   = (u16*)  alloc(4096ull * 1216 * 2);
    u16*   cat_lo   = (u16*)  alloc(4096ull * 1216 * 2);

    hipMemsetAsync(v, 0, 8192ull * 600 * 4, stream);
    hipMemsetAsync(e, 0, 512ull * 600 * 4, stream);

    // ---- prep ----
    k_detect<<<1, 256, 0, stream>>>(emb, flag);
    k_prep_small<<<1, 128, 0, stream>>>(text, asp, lens);
    k_pad_wih<<<(2432 * 320 + 255) / 256, 256, 0, stream>>>(l1_Wih, flag, wiht_hi, wiht_lo);
    k_pad_wih<<<(2432 * 320 + 255) / 256, 256, 0, stream>>>(l2_Wih, flag, wiha_hi, wiha_lo);
    k_whhT<<<(720000 + 255) / 256, 256, 0, stream>>>(l1_Whh, flag, whhT_t);
    k_whhT<<<(720000 + 255) / 256, 256, 0, stream>>>(l2_Whh, flag, whhT_a);
    k_bias<<<10, 256, 0, stream>>>(l1_bih, l1_bhh, l2_bih, l2_bhh, flag, bias_t, bias_a);
    k_small<<<49, 256, 0, stream>>>(pw, lin2_W, lin2_b, fcW, fcb, lin1_b, flag,
                                    smallf, bias_l1);

    // ---- aspect xproj (consumed by fused chunk-0 dispatch) ----
    k_embed_pos<<<(512 * 320 + 255) / 256, 256, 0, stream>>>(emb, asp, 0, 8, 8, flag,
                                                             af_hi, af_lo);
    gemm_bt<<<dim3(8, 38), 256, 0, stream>>>(af_hi, af_lo, 320, wiha_hi, wiha_lo, 320,
        bias_a, xproj_a, 2400, 2400, 320, 0, nullptr, nullptr, nullptr, 0);

    // ---- text path: 4 chunks of 32 positions; chunk 0 fused with aspect ----
    for (int kk = 0; kk < 4; ++kk) {
        int bf = 32 * kk;          // fwd base
        int bb = 96 - 32 * kk;     // bwd base (descending consumption)
        k_embed_pos<<<(2048 * 320 + 255) / 256, 256, 0, stream>>>(emb, text, bf, 32, 128,
                                                                  flag, wfcf_hi, wfcf_lo);
        k_embed_pos<<<(2048 * 320 + 255) / 256, 256, 0, stream>>>(emb, text, bb, 32, 128,
                                                                  flag, wfcb_hi, wfcb_lo);
        gemm_bt<<<dim3(32, 19), 256, 0, stream>>>(wfcf_hi, wfcf_lo, 320,
            wiht_hi, wiht_lo, 320, bias_t, xf, 1200, 1200, 320, 0,
            nullptr, nullptr, nullptr, 0);
        gemm_bt<<<dim3(32, 19), 256, 0, stream>>>(wfcb_hi, wfcb_lo, 320,
            wiht_hi + 1200ull * 320, wiht_lo + 1200ull * 320, 320, bias_t + 1200,
            xb, 1200, 1200, 320, 0, nullptr, nullptr, nullptr, 0);
        int nblk = (kk == 0) ? 256 : 128;   // chunk 0 carries the aspect chains
        k_lstm4<<<nblk, 960, 0, stream>>>(xf, xb, 1200, 32, bf, bb,
            whhT_t, lens, v, 128, kk == 0 ? 1 : 0, hst_t, cst_t, 32,
            xproj_a, whhT_a, lens + 64, e, hst_a, cst_a);
    }

    // ---- phase B prep ----
    k_pad_lin1<<<(2 * 640 * 1216 + 255) / 256, 256, 0, stream>>>(lin1_W, flag,
                                                                 l1w_hi, l1w_lo);

    // ---- two attention iterations (2 chunks of 4096 rows) ----
    for (int iter = 0; iter < 2; ++iter) {
        k_scores<<<8192, 64, 0, stream>>>(v, e, text, asp, l2w_f, l2b_f, iter, a_sm, tg);
        for (int c = 0; c < 2; ++c) {
            int rowoff = c * 4096;
            k_midcat<<<dim3(5, 4096), 256, 0, stream>>>(a_sm, e, v, rowoff, cat_hi, cat_lo);
            gemm_bt<<<dim3(64, 10), 256, 0, stream>>>(cat_hi, cat_lo, 1216,
                l1w_hi + (size_t)iter * 640 * 1216, l1w_lo + (size_t)iter * 640 * 1216,
                1216, bias_l1 + iter * 640,
                nullptr, 0, 600, 1216, 1, tg, pw_f, v, rowoff);
        }
    }

    // ---- final ----
    k_query<<<150, 256, 0, stream>>>(e, asp, query);
    k_final<<<64, 128, 0, stream>>>(v, query, text, fcW_f, fcb_f, flag, d_out);
}

// Round 10
// 1980.228 us; speedup vs baseline: 2.8545x; 1.0489x over previous
//
#include <hip/hip_runtime.h>
#include <hip/hip_bf16.h>
#include <hip/hip_fp16.h>

// RepWalk on MI355X (gfx950). Inputs fp32, output fp32 (verified r4).
// Round 10: LSTM k-loop at its load-instruction floor (r9 confirmed ~20cyc/
// wave-load model; 703 loads/step). This round attacks the non-LSTM ~1.1ms:
//  - gemm_emb: fused emb-gather + fp32->bf16 hi/lo split + MFMA xproj GEMM
//    (deletes 10 k_embed_pos dispatches + staging buffers)
//  - k_scoremid: scores+softmax+tgate+mid+cat in one kernel (deletes 8
//    dispatches + a 20MB v re-read)
//  - merged prep kernels. ~31 dispatches total (was ~45).

typedef unsigned short u16;
typedef __attribute__((ext_vector_type(8))) short short8;
typedef __attribute__((ext_vector_type(4))) float floatx4;

#define NEGV -1e9f
#define MFMA __builtin_amdgcn_mfma_f32_16x16x32_bf16

__device__ __forceinline__ float bf2f(u16 u) {
    union { unsigned int i; float f; } x; x.i = ((unsigned int)u) << 16; return x.f;
}
__device__ __forceinline__ u16 f2bf(float f) {
    unsigned int u = __float_as_uint(f);
    unsigned int r = (u + 0x7fff + ((u >> 16) & 1)) >> 16;
    return (u16)r;
}
__device__ __forceinline__ float sigm(float x) { return 1.f / (1.f + expf(-x)); }
__device__ __forceinline__ float rdf(const void* p, size_t i, int flag) {
    return flag ? ((const float*)p)[i] : bf2f(((const u16*)p)[i]);
}

// ---------------- dtype detect ----------------
__global__ void k_detect(const void* __restrict__ emb, int* __restrict__ flag) {
    __shared__ int cnt;
    if (threadIdx.x == 0) cnt = 0;
    __syncthreads();
    u16 x = ((const u16*)emb)[4096 + threadIdx.x];
    int e = (x >> 7) & 0xFF;
    if (e >= 0x8A) atomicAdd(&cnt, 1);
    __syncthreads();
    if (threadIdx.x == 0) *flag = (cnt > 8) ? 1 : 0;
}

// ---------------- small prep ----------------
__global__ void k_prep_small(const int* __restrict__ text, const int* __restrict__ asp,
                             int* __restrict__ lens) {
    int tid = threadIdx.x;
    if (tid < 64) {
        int c = 0;
        for (int s = 0; s < 128; ++s) c += (text[tid * 128 + s] != 0);
        lens[tid] = c;
    } else if (tid < 128) {
        int b = tid - 64; int c = 0;
        for (int a = 0; a < 8; ++a) c += (asp[b * 8 + a] != 0);
        lens[64 + b] = c;
    }
}

// both Wih layers -> padded [2432,320] hi/lo each
__global__ void k_pad_wih2(const void* __restrict__ W1, const void* __restrict__ W2,
                           const int* __restrict__ flag,
                           u16* __restrict__ d1h, u16* __restrict__ d1l,
                           u16* __restrict__ d2h, u16* __restrict__ d2l) {
    int i = blockIdx.x * 256 + threadIdx.x;
    if (i >= 2 * 2432 * 320) return;
    int f = *flag;
    int layer = i / (2432 * 320), r = i - layer * (2432 * 320);
    int n = r / 320, k = r - n * 320;
    const void* W = layer ? W2 : W1;
    float val = (n < 2400 && k < 300) ? rdf(W, (size_t)n * 300 + k, f) : 0.f;
    u16 hi = f2bf(val);
    float lo = val - bf2f(hi);
    if (layer) { d2h[r] = hi; d2l[r] = f2bf(lo); }
    else       { d1h[r] = hi; d1l[r] = f2bf(lo); }
}

// both Whh layers -> WhhT fp16 [2,300,1200] each
__global__ void k_whhT2(const void* __restrict__ W1, const void* __restrict__ W2,
                        const int* __restrict__ flag,
                        u16* __restrict__ d1, u16* __restrict__ d2) {
    int i = blockIdx.x * 256 + threadIdx.x;
    if (i >= 2 * 720000) return;
    int f = *flag;
    int layer = i / 720000, r = i - layer * 720000;
    int dir = r / 360000, rr = r - dir * 360000;
    int k = rr / 1200, g = rr - k * 1200;
    const void* W = layer ? W2 : W1;
    float val = rdf(W, (size_t)dir * 360000 + (size_t)g * 300 + k, f);
    __half hh = __float2half(val);
    u16 bits = *reinterpret_cast<u16*>(&hh);
    if (layer) d2[r] = bits; else d1[r] = bits;
}

// lin1_W [2,600,1200] -> padded [2,640,1216] hi/lo
__global__ void k_pad_lin1(const void* __restrict__ W, const int* __restrict__ flag,
                           u16* __restrict__ dhi, u16* __restrict__ dlo) {
    int i = blockIdx.x * 256 + threadIdx.x;
    if (i >= 2 * 640 * 1216) return;
    int f = *flag;
    int dir = i / (640 * 1216), r = i - dir * (640 * 1216);
    int n = r / 1216, k = r - n * 1216;
    float val = (n < 600 && k < 1200)
        ? rdf(W, (size_t)dir * 720000 + (size_t)n * 1200 + k, f) : 0.f;
    u16 hi = f2bf(val);
    dhi[i] = hi;
    dlo[i] = f2bf(val - bf2f(hi));
}

// smallf = pw(8192)|l2w(1200)|l2b(2)|fcw(1800)|fcb(3); bl[1280]; bias_t/a[2400]
__global__ void k_small(const void* pw, const void* l2w, const void* l2b,
                        const void* fcw, const void* fcb, const void* lb,
                        const void* b1i, const void* b1h, const void* b2i, const void* b2h,
                        const int* __restrict__ flag,
                        float* __restrict__ dst, float* __restrict__ bl,
                        float* __restrict__ bt, float* __restrict__ ba) {
    int i = blockIdx.x * 256 + threadIdx.x;
    int f = *flag;
    if (i < 8192)            dst[i] = rdf(pw, i, f);
    else if (i < 9392)       dst[i] = rdf(l2w, i - 8192, f);
    else if (i < 9394)       dst[i] = rdf(l2b, i - 9392, f);
    else if (i < 11194)      dst[i] = rdf(fcw, i - 9394, f);
    else if (i < 11197)      dst[i] = rdf(fcb, i - 11194, f);
    if (i < 1280) {
        int dir = i / 640, c = i - dir * 640;
        bl[i] = (c < 600) ? rdf(lb, dir * 600 + c, f) : 0.f;
    }
    if (i < 2400) {
        bt[i] = rdf(b1i, i, f) + rdf(b1h, i, f);
        ba[i] = rdf(b2i, i, f) + rdf(b2h, i, f);
    }
}

// ---------------- fused gather xproj GEMM ----------------
// C[M,nstore] = gather(emb, ids)[M,300pad320] @ (Bhi+Blo)[Npad,320]^T + bias.
// A row m: b = m/rpb, j = m%rpb, id = ids[b*stride + base + j]; fp32 emb split
// to bf16 hi/lo in registers (exact path when inputs bf16: lo=0).
__global__ __launch_bounds__(256) void gemm_emb(
    const void* __restrict__ emb, const int* __restrict__ ids,
    int base, int rpb, int stride, const int* __restrict__ flag,
    const u16* __restrict__ Bhi, const u16* __restrict__ Blo,
    const float* __restrict__ bias,
    float* __restrict__ C, int ldc, int nstore)
{
    int f = *flag;
    int tid = threadIdx.x;
    int wave = tid >> 6, lane = tid & 63;
    int l15 = lane & 15, quad = lane >> 4;
    int m0 = blockIdx.x * 64 + wave * 16;
    int n0 = blockIdx.y * 64;

    int m = m0 + l15;
    int b = m / rpb, j = m - b * rpb;
    int id = ids[b * stride + base + j];
    const float* arow_f = (const float*)emb + (size_t)id * 300;
    const u16*   arow_b = (const u16*)emb + (size_t)id * 300;

    const u16* Bp  = Bhi + (size_t)(n0 + l15) * 320 + quad * 8;
    const u16* Bp2 = Blo + (size_t)(n0 + l15) * 320 + quad * 8;

    floatx4 acc0 = {0.f, 0.f, 0.f, 0.f};
    floatx4 acc1 = acc0, acc2 = acc0, acc3 = acc0;

    for (int kc = 0; kc < 10; ++kc) {
        int ko = kc * 32 + quad * 8;
        short8 ahi, alo;
        if (f) {
            if (ko + 8 <= 300) {
                float4 fa = *(const float4*)(arow_f + ko);
                float4 fb = *(const float4*)(arow_f + ko + 4);
                float vv[8] = {fa.x, fa.y, fa.z, fa.w, fb.x, fb.y, fb.z, fb.w};
                #pragma unroll
                for (int t = 0; t < 8; ++t) {
                    u16 h = f2bf(vv[t]);
                    ahi[t] = (short)h;
                    alo[t] = (short)f2bf(vv[t] - bf2f(h));
                }
            } else {
                #pragma unroll
                for (int t = 0; t < 8; ++t) {
                    int k = ko + t;
                    float vv = (k < 300) ? arow_f[k] : 0.f;
                    u16 h = f2bf(vv);
                    ahi[t] = (short)h;
                    alo[t] = (short)f2bf(vv - bf2f(h));
                }
            }
        } else {
            #pragma unroll
            for (int t = 0; t < 8; ++t) {
                int k = ko + t;
                ahi[t] = (k < 300) ? (short)arow_b[k] : (short)0;
                alo[t] = 0;
            }
        }
        int ko2 = kc * 32;
        short8 bh0 = *(const short8*)(Bp + ko2);
        short8 bh1 = *(const short8*)(Bp + (size_t)16 * 320 + ko2);
        short8 bh2 = *(const short8*)(Bp + (size_t)32 * 320 + ko2);
        short8 bh3 = *(const short8*)(Bp + (size_t)48 * 320 + ko2);
        short8 bl0 = *(const short8*)(Bp2 + ko2);
        short8 bl1 = *(const short8*)(Bp2 + (size_t)16 * 320 + ko2);
        short8 bl2 = *(const short8*)(Bp2 + (size_t)32 * 320 + ko2);
        short8 bl3 = *(const short8*)(Bp2 + (size_t)48 * 320 + ko2);
        acc0 = MFMA(ahi, bh0, acc0, 0, 0, 0);
        acc1 = MFMA(ahi, bh1, acc1, 0, 0, 0);
        acc2 = MFMA(ahi, bh2, acc2, 0, 0, 0);
        acc3 = MFMA(ahi, bh3, acc3, 0, 0, 0);
        acc0 = MFMA(ahi, bl0, acc0, 0, 0, 0);
        acc1 = MFMA(ahi, bl1, acc1, 0, 0, 0);
        acc2 = MFMA(ahi, bl2, acc2, 0, 0, 0);
        acc3 = MFMA(ahi, bl3, acc3, 0, 0, 0);
        acc0 = MFMA(alo, bh0, acc0, 0, 0, 0);
        acc1 = MFMA(alo, bh1, acc1, 0, 0, 0);
        acc2 = MFMA(alo, bh2, acc2, 0, 0, 0);
        acc3 = MFMA(alo, bh3, acc3, 0, 0, 0);
    }

    #pragma unroll
    for (int c = 0; c < 4; ++c) {
        floatx4 acc = (c == 0) ? acc0 : (c == 1) ? acc1 : (c == 2) ? acc2 : acc3;
        int col = n0 + c * 16 + l15;
        if (col >= nstore) continue;
        float bb = bias[col];
        #pragma unroll
        for (int r = 0; r < 4; ++r) {
            int row = m0 + quad * 4 + r;
            C[(size_t)row * ldc + col] = acc[r] + bb;
        }
    }
}

// ---------------- MFMA GEMM (lin1): C = (Ahi+Alo)@(Bhi+Blo)^T, fused epilogue ----
__global__ __launch_bounds__(256) void gemm_bt(
    const u16* __restrict__ Ahi, const u16* __restrict__ Alo, int lda,
    const u16* __restrict__ Bhi, const u16* __restrict__ Blo, int ldb,
    const float* __restrict__ bias,
    int nstore, int K,
    const float* __restrict__ tg, const float* __restrict__ pw, float* __restrict__ vio,
    int mrowoff)
{
    int tid = threadIdx.x;
    int wave = tid >> 6, lane = tid & 63;
    int l15 = lane & 15, quad = lane >> 4;
    int m0 = blockIdx.x * 64 + wave * 16;
    int n0 = blockIdx.y * 64;

    const u16* Ap  = Ahi + (size_t)(m0 + l15) * lda + quad * 8;
    const u16* Ap2 = Alo + (size_t)(m0 + l15) * lda + quad * 8;
    const u16* Bp  = Bhi + (size_t)(n0 + l15) * ldb + quad * 8;
    const u16* Bp2 = Blo + (size_t)(n0 + l15) * ldb + quad * 8;

    floatx4 acc0 = {0.f, 0.f, 0.f, 0.f};
    floatx4 acc1 = acc0, acc2 = acc0, acc3 = acc0;

    int nk = K >> 5;
    for (int kc = 0; kc < nk; ++kc) {
        int ko = kc * 32;
        short8 bh0 = *(const short8*)(Bp + ko);
        short8 bh1 = *(const short8*)(Bp + (size_t)16 * ldb + ko);
        short8 bh2 = *(const short8*)(Bp + (size_t)32 * ldb + ko);
        short8 bh3 = *(const short8*)(Bp + (size_t)48 * ldb + ko);
        short8 bl0 = *(const short8*)(Bp2 + ko);
        short8 bl1 = *(const short8*)(Bp2 + (size_t)16 * ldb + ko);
        short8 bl2 = *(const short8*)(Bp2 + (size_t)32 * ldb + ko);
        short8 bl3 = *(const short8*)(Bp2 + (size_t)48 * ldb + ko);
        short8 a  = *(const short8*)(Ap + ko);
        short8 al = *(const short8*)(Ap2 + ko);
        acc0 = MFMA(a, bh0, acc0, 0, 0, 0);
        acc1 = MFMA(a, bh1, acc1, 0, 0, 0);
        acc2 = MFMA(a, bh2, acc2, 0, 0, 0);
        acc3 = MFMA(a, bh3, acc3, 0, 0, 0);
        acc0 = MFMA(a, bl0, acc0, 0, 0, 0);
        acc1 = MFMA(a, bl1, acc1, 0, 0, 0);
        acc2 = MFMA(a, bl2, acc2, 0, 0, 0);
        acc3 = MFMA(a, bl3, acc3, 0, 0, 0);
        acc0 = MFMA(al, bh0, acc0, 0, 0, 0);
        acc1 = MFMA(al, bh1, acc1, 0, 0, 0);
        acc2 = MFMA(al, bh2, acc2, 0, 0, 0);
        acc3 = MFMA(al, bh3, acc3, 0, 0, 0);
    }

    #pragma unroll
    for (int c = 0; c < 4; ++c) {
        floatx4 acc = (c == 0) ? acc0 : (c == 1) ? acc1 : (c == 2) ? acc2 : acc3;
        int col = n0 + c * 16 + l15;
        if (col >= nstore) continue;
        float bb = bias[col];
        #pragma unroll
        for (int r = 0; r < 4; ++r) {
            int row = m0 + quad * 4 + r;
            float val = acc[r] + bb;
            val = val > 0.f ? val : 0.01f * val;      // leaky_relu
            int rg = row + mrowoff;
            float t = tg[rg];
            size_t vi = (size_t)rg * 600 + col;
            float vv = vio[vi];
            vio[vi] = pw[rg] * ((1.f - t) * val + t * vv);
        }
    }
}

// ---------------- LSTM recurrence (r9 structure, unchanged) ----------------
__global__ __launch_bounds__(960, 1) void k_lstm4(
    const float* __restrict__ xf, const float* __restrict__ xb, int ldx, int rpb,
    int base_f, int base_b, const u16* __restrict__ whhT,
    const int* __restrict__ lens, float* __restrict__ out, int T, int init,
    float* __restrict__ hst, float* __restrict__ cst, int nsteps,
    const float* __restrict__ xa, const u16* __restrict__ whhA,
    const int* __restrict__ lensA, float* __restrict__ outA,
    float* __restrict__ hstA, float* __restrict__ cstA)
{
    __shared__ float h_s[300];
    __shared__ float part[6][1200];
    int blk = blockIdx.x;
    if (blk >= 128) {                     // fused aspect chain
        blk -= 128;
        xf = xa; xb = xa + 1200; ldx = 2400; rpb = 8;
        base_f = 0; base_b = 0;
        whhT = whhA; lens = lensA; out = outA; T = 8; init = 1;
        hst = hstA; cst = cstA; nsteps = 8;
    }
    int tid = threadIdx.x;
    int g6 = tid / 160, u = tid - g6 * 160;
    bool act = (u < 150);
    int b = blk >> 1, dir = blk & 1;
    int len = lens[b];
    float c = 0.f;
    if (tid < 300) {
        h_s[tid] = init ? 0.f : hst[(size_t)blk * 300 + tid];
        c = init ? 0.f : cst[(size_t)blk * 300 + tid];
    }
    __syncthreads();
    const u16* wbase = whhT + (size_t)dir * 360000 + (size_t)g6 * 50 * 1200 + 8 * u;

    for (int s = 0; s < nsteps; ++s) {
        int pos = dir ? (base_b + nsteps - 1 - s) : (base_f + s);
        if (pos >= len) continue;           // block-uniform skip
        if (act) {
            float a0 = 0.f, a1 = 0.f, a2 = 0.f, a3 = 0.f;
            float a4 = 0.f, a5 = 0.f, a6 = 0.f, a7 = 0.f;
            const u16* wp = wbase;
            const float* hs = h_s + g6 * 50;
            #pragma unroll 10
            for (int i = 0; i < 50; ++i) {
                float hk = hs[i];
                uint4 wv = *(const uint4*)wp;
                wp += 1200;
                float2 f0 = __half22float2(*(__half2*)&wv.x);
                float2 f1 = __half22float2(*(__half2*)&wv.y);
                float2 f2 = __half22float2(*(__half2*)&wv.z);
                float2 f3 = __half22float2(*(__half2*)&wv.w);
                a0 = fmaf(hk, f0.x, a0); a1 = fmaf(hk, f0.y, a1);
                a2 = fmaf(hk, f1.x, a2); a3 = fmaf(hk, f1.y, a3);
                a4 = fmaf(hk, f2.x, a4); a5 = fmaf(hk, f2.y, a5);
                a6 = fmaf(hk, f3.x, a6); a7 = fmaf(hk, f3.y, a7);
            }
            float* pp = &part[g6][8 * u];
            float4 w0 = {a0, a1, a2, a3};
            float4 w1 = {a4, a5, a6, a7};
            *(float4*)pp = w0;
            *(float4*)(pp + 4) = w1;
        }
        __syncthreads();
        if (tid < 300) {
            const float* xr = dir ? (xb + (size_t)(b * rpb + pos - base_b) * ldx)
                                  : (xf + (size_t)(b * rpb + pos - base_f) * ldx);
            float gi = xr[tid], gf = xr[300 + tid], gg = xr[600 + tid], go = xr[900 + tid];
            #pragma unroll
            for (int g = 0; g < 6; ++g) {
                gi += part[g][tid];
                gf += part[g][300 + tid];
                gg += part[g][600 + tid];
                go += part[g][900 + tid];
            }
            gi = sigm(gi); gf = sigm(gf); gg = tanhf(gg); go = sigm(go);
            c = gf * c + gi * gg;
            float hn = go * tanhf(c);
            out[((size_t)b * T + pos) * 600 + dir * 300 + tid] = hn;
            h_s[tid] = hn;
        }
        __syncthreads();
    }
    if (tid < 300) {
        hst[(size_t)blk * 300 + tid] = h_s[tid];
        cst[(size_t)blk * 300 + tid] = c;
    }
}

// ---------------- fused scores+softmax+tgate+mid+cat ----------------
// one block (128 thr) per row in [rowoff, rowoff+nrows)
__global__ __launch_bounds__(128) void k_scoremid(
    const float* __restrict__ v, const float* __restrict__ e,
    const int* __restrict__ text, const int* __restrict__ asp,
    const float* __restrict__ l2w, const float* __restrict__ l2b, int iter,
    int rowoff, float* __restrict__ tg,
    u16* __restrict__ cat_hi, u16* __restrict__ cat_lo)
{
    __shared__ float vs[600];
    __shared__ float red[2][9];
    __shared__ float alpha_s[8];
    int row = rowoff + blockIdx.x;
    int rl = blockIdx.x;
    int b = row >> 7;
    int t = threadIdx.x, wv = t >> 6, lane = t & 63;
    const float* vrow = v + (size_t)row * 600;
    const float* eb = e + (size_t)b * 4800;
    const float* w2 = l2w + iter * 600;

    for (int d = t; d < 600; d += 128) vs[d] = vrow[d];
    __syncthreads();

    float acc[9];
    #pragma unroll
    for (int j = 0; j < 9; ++j) acc[j] = 0.f;
    for (int d = t; d < 600; d += 128) {
        float vv = vs[d];
        #pragma unroll
        for (int a = 0; a < 8; ++a) acc[a] += vv * eb[a * 600 + d];
        acc[8] += vv * w2[d];
    }
    #pragma unroll
    for (int off = 32; off >= 1; off >>= 1) {
        #pragma unroll
        for (int j = 0; j < 9; ++j) acc[j] += __shfl_down(acc[j], off, 64);
    }
    if (lane == 0) {
        #pragma unroll
        for (int j = 0; j < 9; ++j) red[wv][j] = acc[j];
    }
    __syncthreads();
    if (t == 0) {
        float dots[9];
        #pragma unroll
        for (int j = 0; j < 9; ++j) dots[j] = red[0][j] + red[1][j];
        tg[row] = sigm(dots[8] + l2b[iter]);
        bool sm = (text[row] != 0);
        float sc[8]; float mx = -INFINITY;
        #pragma unroll
        for (int a = 0; a < 8; ++a) {
            sc[a] = (sm && asp[b * 8 + a] != 0) ? dots[a] : NEGV;
            mx = fmaxf(mx, sc[a]);
        }
        float den = 0.f;
        #pragma unroll
        for (int a = 0; a < 8; ++a) { sc[a] = expf(sc[a] - mx); den += sc[a]; }
        float inv = 1.f / den;
        #pragma unroll
        for (int a = 0; a < 8; ++a) alpha_s[a] = sc[a] * inv;
    }
    __syncthreads();
    for (int d = t; d < 1216; d += 128) {
        float val;
        if (d < 600) {
            float m = 0.f;
            #pragma unroll
            for (int a = 0; a < 8; ++a) m += alpha_s[a] * eb[a * 600 + d];
            val = m;
        } else if (d < 1200) {
            val = vs[d - 600];
        } else {
            val = 0.f;
        }
        u16 hi = f2bf(val);
        cat_hi[(size_t)rl * 1216 + d] = hi;
        cat_lo[(size_t)rl * 1216 + d] = f2bf(val - bf2f(hi));
    }
}

// ---------------- final ----------------
__global__ void k_query(const float* __restrict__ e, const int* __restrict__ asp,
                        float* __restrict__ q) {
    int i = blockIdx.x * 256 + threadIdx.x;
    if (i >= 64 * 600) return;
    int b = i / 600, d = i - b * 600;
    float m = NEGV;
    for (int a = 0; a < 8; ++a)
        if (asp[b * 8 + a] != 0) m = fmaxf(m, e[(size_t)b * 4800 + a * 600 + d]);
    q[i] = m;
}

__global__ __launch_bounds__(128) void k_final(
    const float* __restrict__ v, const float* __restrict__ q,
    const int* __restrict__ text, const float* __restrict__ fcW,
    const float* __restrict__ fcb, const int* __restrict__ flag, void* __restrict__ outv)
{
    __shared__ float red[128];
    __shared__ float al[128];
    __shared__ float zz[600];
    int b = blockIdx.x, s = threadIdx.x;
    const float* vrow = v + (size_t)(b * 128 + s) * 600;
    const float* qb = q + (size_t)b * 600;
    float sc = 0.f;
    for (int d = 0; d < 600; ++d) sc += vrow[d] * qb[d];
    if (text[b * 128 + s] == 0) sc = NEGV;
    red[s] = sc; __syncthreads();
    for (int off = 64; off >= 1; off >>= 1) {
        if (s < off) red[s] = fmaxf(red[s], red[s + off]);
        __syncthreads();
    }
    float mx = red[0]; __syncthreads();
    float ex = expf(sc - mx);
    red[s] = ex; __syncthreads();
    for (int off = 64; off >= 1; off >>= 1) {
        if (s < off) red[s] += red[s + off];
        __syncthreads();
    }
    float alpha = ex / red[0];
    al[s] = alpha; __syncthreads();
    for (int d = s; d < 600; d += 128) {
        float z = 0.f;
        for (int s2 = 0; s2 < 128; ++s2) z += al[s2] * v[(size_t)(b * 128 + s2) * 600 + d];
        zz[d] = z;
    }
    __syncthreads();
    if (s < 3) {
        float o = 0.f;
        for (int d = 0; d < 600; ++d) o += zz[d] * fcW[s * 600 + d];
        o += fcb[s];
        if (*flag) ((float*)outv)[b * 3 + s] = o;
        else       ((u16*)outv)[b * 3 + s] = f2bf(o);
    }
}

// ---------------- host launch ----------------
extern "C" void kernel_launch(void* const* d_in, const int* in_sizes, int n_in,
                              void* d_out, int out_size, void* d_ws, size_t ws_size,
                              hipStream_t stream) {
    const int*  text   = (const int*)d_in[0];
    const int*  asp    = (const int*)d_in[1];
    const void* pw     = d_in[2];
    const void* emb    = d_in[3];
    const void* l1_Wih = d_in[4];
    const void* l1_Whh = d_in[5];
    const void* l1_bih = d_in[6];
    const void* l1_bhh = d_in[7];
    const void* l2_Wih = d_in[8];
    const void* l2_Whh = d_in[9];
    const void* l2_bih = d_in[10];
    const void* l2_bhh = d_in[11];
    const void* lin1_W = d_in[12];
    const void* lin1_b = d_in[13];
    const void* lin2_W = d_in[14];
    const void* lin2_b = d_in[15];
    const void* fcW    = d_in[16];
    const void* fcb    = d_in[17];
    (void)ws_size; (void)n_in; (void)in_sizes; (void)out_size;

    char* w = (char*)d_ws;
    size_t off = 0;
    auto alloc = [&](size_t bytes) -> void* {
        void* p = w + off;
        off += (bytes + 255) & ~(size_t)255;
        return p;
    };
    // ---- persistent (~23 MB) ----
    int*   flag     = (int*)  alloc(4);
    int*   lens     = (int*)  alloc(128ull * 4);
    float* bias_t   = (float*)alloc(2400ull * 4);
    float* bias_a   = (float*)alloc(2400ull * 4);
    float* bias_l1  = (float*)alloc(1280ull * 4);
    float* smallf   = (float*)alloc(11197ull * 4);
    float* tg       = (float*)alloc(8192ull * 4);
    float* query    = (float*)alloc(64ull * 600 * 4);
    float* hst_t    = (float*)alloc(128ull * 300 * 4);
    float* cst_t    = (float*)alloc(128ull * 300 * 4);
    float* hst_a    = (float*)alloc(128ull * 300 * 4);
    float* cst_a    = (float*)alloc(128ull * 300 * 4);
    float* e        = (float*)alloc(512ull * 600 * 4);
    float* v        = (float*)alloc(8192ull * 600 * 4);
    float* pw_f     = smallf;
    float* l2w_f    = smallf + 8192;
    float* l2b_f    = smallf + 9392;
    float* fcW_f    = smallf + 9394;
    float* fcb_f    = smallf + 11194;
    // ---- phase region (union ~32 MB) ----
    size_t phase_off = off;
    // phase A (LSTM)
    u16*   wiht_hi  = (u16*)  alloc(2432ull * 320 * 2);
    u16*   wiht_lo  = (u16*)  alloc(2432ull * 320 * 2);
    u16*   wiha_hi  = (u16*)  alloc(2432ull * 320 * 2);
    u16*   wiha_lo  = (u16*)  alloc(2432ull * 320 * 2);
    u16*   whhT_t   = (u16*)  alloc(720000ull * 2);   // fp16
    u16*   whhT_a   = (u16*)  alloc(720000ull * 2);   // fp16
    float* xf       = (float*)alloc(2048ull * 1200 * 4);
    float* xb       = (float*)alloc(2048ull * 1200 * 4);
    float* xproj_a  = (float*)alloc(512ull * 2400 * 4);
    // phase B (attention) aliases phase A
    off = phase_off;
    u16*   l1w_hi   = (u16*)  alloc(2ull * 640 * 1216 * 2);
    u16*   l1w_lo   = (u16*)  alloc(2ull * 640 * 1216 * 2);
    u16*   cat_hi   = (u16*)  alloc(4096ull * 1216 * 2);
    u16*   cat_lo   = (u16*)  alloc(4096ull * 1216 * 2);

    hipMemsetAsync(v, 0, 8192ull * 600 * 4, stream);
    hipMemsetAsync(e, 0, 512ull * 600 * 4, stream);

    // ---- prep (merged) ----
    k_detect<<<1, 256, 0, stream>>>(emb, flag);
    k_prep_small<<<1, 128, 0, stream>>>(text, asp, lens);
    k_pad_wih2<<<(2 * 2432 * 320 + 255) / 256, 256, 0, stream>>>(
        l1_Wih, l2_Wih, flag, wiht_hi, wiht_lo, wiha_hi, wiha_lo);
    k_whhT2<<<(2 * 720000 + 255) / 256, 256, 0, stream>>>(
        l1_Whh, l2_Whh, flag, whhT_t, whhT_a);
    k_small<<<49, 256, 0, stream>>>(pw, lin2_W, lin2_b, fcW, fcb, lin1_b,
                                    l1_bih, l1_bhh, l2_bih, l2_bhh, flag,
                                    smallf, bias_l1, bias_t, bias_a);

    // ---- aspect xproj (fused gather; consumed by chunk-0 lstm dispatch) ----
    gemm_emb<<<dim3(8, 38), 256, 0, stream>>>(emb, asp, 0, 8, 8, flag,
        wiha_hi, wiha_lo, bias_a, xproj_a, 2400, 2400);

    // ---- text path: 4 chunks of 32 positions; chunk 0 carries aspect chains ----
    for (int kk = 0; kk < 4; ++kk) {
        int bf = 32 * kk;          // fwd base
        int bb = 96 - 32 * kk;     // bwd base (descending consumption)
        gemm_emb<<<dim3(32, 19), 256, 0, stream>>>(emb, text, bf, 32, 128, flag,
            wiht_hi, wiht_lo, bias_t, xf, 1200, 1200);
        gemm_emb<<<dim3(32, 19), 256, 0, stream>>>(emb, text, bb, 32, 128, flag,
            wiht_hi + 1200ull * 320, wiht_lo + 1200ull * 320, bias_t + 1200,
            xb, 1200, 1200);
        int nblk = (kk == 0) ? 256 : 128;
        k_lstm4<<<nblk, 960, 0, stream>>>(xf, xb, 1200, 32, bf, bb,
            whhT_t, lens, v, 128, kk == 0 ? 1 : 0, hst_t, cst_t, 32,
            xproj_a, whhT_a, lens + 64, e, hst_a, cst_a);
    }

    // ---- phase B prep (after last phase-A consumer) ----
    k_pad_lin1<<<(2 * 640 * 1216 + 255) / 256, 256, 0, stream>>>(lin1_W, flag,
                                                                 l1w_hi, l1w_lo);

    // ---- two attention iterations (2 chunks of 4096 rows, fused scoremid) ----
    for (int iter = 0; iter < 2; ++iter) {
        for (int c = 0; c < 2; ++c) {
            int rowoff = c * 4096;
            k_scoremid<<<4096, 128, 0, stream>>>(v, e, text, asp, l2w_f, l2b_f,
                iter, rowoff, tg, cat_hi, cat_lo);
            gemm_bt<<<dim3(64, 10), 256, 0, stream>>>(cat_hi, cat_lo, 1216,
                l1w_hi + (size_t)iter * 640 * 1216, l1w_lo + (size_t)iter * 640 * 1216,
                1216, bias_l1 + iter * 640, 600, 1216,
                tg, pw_f, v, rowoff);
        }
    }

    // ---- final ----
    k_query<<<150, 256, 0, stream>>>(e, asp, query);
    k_final<<<64, 128, 0, stream>>>(v, query, text, fcW_f, fcb_f, flag, d_out);
}